// Round 3
// baseline (81741.669 us; speedup 1.0000x reference)
//
#include <hip/hip_runtime.h>

// ---------------------------------------------------------------------------
// Decoder_49005576847865 — persistent single-kernel incremental decoder.
//   B=16, d=512, H=8 (dh=64), L=4, dff=2048, Lenc=2048, 16 steps, vocab=256.
// Round 3: ONE mega-kernel (256 blocks x 256 threads, 1 block/CU co-resident)
//   with a software grid barrier. Round-2 math unchanged (enc-identity
//   cross-attn, no K/V cache): ~530 launches -> 2 (memset + kernel).
// ---------------------------------------------------------------------------

typedef unsigned short ushort_t;
typedef __attribute__((ext_vector_type(4))) float f32x4;
typedef __attribute__((ext_vector_type(8))) unsigned short us8;
typedef __attribute__((ext_vector_type(4))) unsigned short us4;

#define NB 256
#define NTHR 256

__device__ __forceinline__ float bf2f(ushort_t u) {
    union { unsigned int i; float f; } v; v.i = ((unsigned int)u) << 16; return v.f;
}
__device__ __forceinline__ ushort_t f2bf(float f) {
    union { unsigned int i; float f; } v; v.f = f;
    return (ushort_t)((v.i + 0x7FFF + ((v.i >> 16) & 1)) >> 16);   // RNE
}
__device__ __forceinline__ float wave_sum(float v) {
    #pragma unroll
    for (int m = 32; m; m >>= 1) v += __shfl_xor(v, m);
    return v;
}

// ---- software grid barrier (device scope; all NB blocks must be resident) --
__device__ __forceinline__ void gsync(unsigned* cnt, unsigned* gen) {
    __syncthreads();
    if (threadIdx.x == 0) {
        __threadfence();   // release: my block's stores visible at agent scope
        unsigned g = __hip_atomic_load(gen, __ATOMIC_RELAXED, __HIP_MEMORY_SCOPE_AGENT);
        unsigned a = __hip_atomic_fetch_add(cnt, 1u, __ATOMIC_ACQ_REL, __HIP_MEMORY_SCOPE_AGENT);
        if (a == NB - 1u) {
            __hip_atomic_store(cnt, 0u, __ATOMIC_RELAXED, __HIP_MEMORY_SCOPE_AGENT);
            __hip_atomic_fetch_add(gen, 1u, __ATOMIC_ACQ_REL, __HIP_MEMORY_SCOPE_AGENT);
        } else {
            while (__hip_atomic_load(gen, __ATOMIC_ACQUIRE, __HIP_MEMORY_SCOPE_AGENT) == g)
                __builtin_amdgcn_s_sleep(1);
        }
        __threadfence();   // acquire: invalidate stale cached lines
    }
    __syncthreads();
}

// ---- wave-local LN of one 512 row into smem (no syncs; same-wave use) ------
__device__ __forceinline__ void stage_ln_wave(const float* __restrict__ row,
                                              const float* __restrict__ g,
                                              const float* __restrict__ be,
                                              int use_ln, float* xs, int lane) {
    float loc[8];
    float s = 0.f;
    #pragma unroll
    for (int i = 0; i < 8; i++) { loc[i] = row[lane + i * 64]; s += loc[i]; }
    if (use_ln) {
        s = wave_sum(s);
        float mu = s * (1.f / 512.f);
        float var = 0.f;
        #pragma unroll
        for (int i = 0; i < 8; i++) { float d = loc[i] - mu; var += d * d; }
        var = wave_sum(var);
        float rstd = rsqrtf(var * (1.f / 512.f) + 1e-6f);
        #pragma unroll
        for (int i = 0; i < 8; i++) {
            int c = lane + i * 64;
            xs[c] = (loc[i] - mu) * rstd * g[c] + be[c];
        }
    } else {
        #pragma unroll
        for (int i = 0; i < 8; i++) xs[lane + i * 64] = loc[i];
    }
}

// ---- block-wide LN of one 512 row (256 threads, 2 elems each) --------------
__device__ __forceinline__ void ln512_block(const float* __restrict__ row,
                                            const float* __restrict__ g,
                                            const float* __restrict__ be,
                                            int use_ln, float* dst, float* red) {
    int tid = threadIdx.x;
    float a = row[tid], b = row[tid + 256];
    if (use_ln) {
        float s = wave_sum(a + b);
        if ((tid & 63) == 0) red[tid >> 6] = s;
        __syncthreads();
        float mu = (red[0] + red[1] + red[2] + red[3]) * (1.f / 512.f);
        float d0 = a - mu, d1 = b - mu;
        float v = wave_sum(d0 * d0 + d1 * d1);
        if ((tid & 63) == 0) red[4 + (tid >> 6)] = v;
        __syncthreads();
        float rstd = rsqrtf((red[4] + red[5] + red[6] + red[7]) * (1.f / 512.f) + 1e-6f);
        dst[tid]       = d0 * rstd * g[tid] + be[tid];
        dst[tid + 256] = d1 * rstd * g[tid + 256] + be[tid + 256];
    } else {
        dst[tid] = a; dst[tid + 256] = b;
    }
    __syncthreads();
}

// ---- wave-local dot: 64 cols (lane=col), runtime K, 4 accumulators ---------
__device__ __forceinline__ float wdot(const float* xs, const float* __restrict__ W,
                                      int K, int col, int N) {
    const float* Wp = W + col;
    float a0 = 0.f, a1 = 0.f, a2 = 0.f, a3 = 0.f;
    for (int r = 0; r < K; r += 4) {
        a0 += xs[r]     * Wp[(size_t)r * N];
        a1 += xs[r + 1] * Wp[(size_t)(r + 1) * N];
        a2 += xs[r + 2] * Wp[(size_t)(r + 2) * N];
        a3 += xs[r + 3] * Wp[(size_t)(r + 3) * N];
    }
    return (a0 + a1) + (a2 + a3);
}

// ---- block split-K (K=512, 4 waves x 128 rows); result valid on wave 0 -----
__device__ __forceinline__ float gemv_splitk(const float* xa, const float* __restrict__ W,
                                             int col0, int N, float* part) {
    int lane = threadIdx.x & 63, w = threadIdx.x >> 6;
    const float* Wp = W + ((size_t)(w * 128)) * N + col0 + lane;
    const float* xp = xa + w * 128;
    float a0 = 0.f, a1 = 0.f, a2 = 0.f, a3 = 0.f;
    for (int r = 0; r < 128; r += 4) {
        a0 += xp[r]     * Wp[(size_t)r * N];
        a1 += xp[r + 1] * Wp[(size_t)(r + 1) * N];
        a2 += xp[r + 2] * Wp[(size_t)(r + 2) * N];
        a3 += xp[r + 3] * Wp[(size_t)(r + 3) * N];
    }
    part[w * 64 + lane] = (a0 + a1) + (a2 + a3);
    __syncthreads();
    float r = 0.f;
    if (w == 0) r = part[lane] + part[64 + lane] + part[128 + lane] + part[192 + lane];
    return r;
}

struct Args {
    const float *enc, *encIn, *embW, *embB, *outW, *outB;
    const float *selfW, *selfB, *crossW, *crossB;
    const float *fW1, *fb1, *fW2, *fb2, *lng, *lnb;
    float* out;
    unsigned *cnt, *gen;
    float *pad, *pos, *x0, *qbuf, *qc, *y1, *y2, *y3, *attnb;
    float *lny1, *lny2, *qt, *Pm2, *Ps2, *Pz, *tmpb, *pf2, *selfK, *selfV;
    ushort_t* encbf;
};

// ---- flash cross-attn stage body (one (b, chunk) per block) ----------------
template<int BF16>
__device__ __forceinline__ void flash_stage(const Args& A, float* sm, int bid, int tid) {
    int b = bid >> 4, c = bid & 15;
    float* qts = sm;            // [8][520]
    float* rows = sm + 4160;    // [16][520]
    float* lge  = sm + 12480;   // [8][16]
    float* mhp  = sm + 12608;
    float* shp  = sm + 12616;
    float* fhp  = sm + 12624;
    for (int i = tid; i < 4096; i += 256)
        qts[(i >> 9) * 520 + (i & 511)] = A.qt[(size_t)b * 4096 + i];
    if (tid < 8) { mhp[tid] = -1e30f; shp[tid] = 0.f; fhp[tid] = 1.f; }
    int h = tid >> 5, ii = tid & 31;
    f32x4 z4[4];
    #pragma unroll
    for (int jj = 0; jj < 4; jj++) z4[jj] = (f32x4){0.f, 0.f, 0.f, 0.f};

    us8 pf[4];
    float4 pf32[8];
    auto LOAD = [&](int g) {
        int key0 = c * 128 + g * 16;
        if (BF16) {
            #pragma unroll
            for (int it = 0; it < 4; it++) {
                int off = it * 2048 + tid * 8;
                int kr = off >> 9, D = off & 511;
                pf[it] = *(const us8*)(A.encbf + ((size_t)b * 2048 + key0 + kr) * 512 + D);
            }
        } else {
            #pragma unroll
            for (int it = 0; it < 8; it++) {
                int off = it * 1024 + tid * 4;
                int kr = off >> 9, D = off & 511;
                pf32[it] = *(const float4*)(A.enc + ((size_t)b * 2048 + key0 + kr) * 512 + D);
            }
        }
    };
    auto STORE = [&]() {
        if (BF16) {
            #pragma unroll
            for (int it = 0; it < 4; it++) {
                int off = it * 2048 + tid * 8;
                int kr = off >> 9, D = off & 511;
                float4 lo = {bf2f(pf[it][0]), bf2f(pf[it][1]), bf2f(pf[it][2]), bf2f(pf[it][3])};
                float4 hi = {bf2f(pf[it][4]), bf2f(pf[it][5]), bf2f(pf[it][6]), bf2f(pf[it][7])};
                *(float4*)(rows + kr * 520 + D)     = lo;
                *(float4*)(rows + kr * 520 + D + 4) = hi;
            }
        } else {
            #pragma unroll
            for (int it = 0; it < 8; it++) {
                int off = it * 1024 + tid * 4;
                int kr = off >> 9, D = off & 511;
                *(float4*)(rows + kr * 520 + D) = pf32[it];
            }
        }
    };

    LOAD(0);
    __syncthreads();   // qts staged
    for (int g = 0; g < 8; g++) {
        STORE();
        if (g < 7) LOAD(g + 1);
        __syncthreads();
        {   // logits: 16 keys x 8 heads, 2-way K split
            int kr = tid >> 4, hh = (tid >> 1) & 7, part = tid & 1;
            const float* q = qts + hh * 520 + part * 256;
            const float* e = rows + kr * 520 + part * 256;
            float a0 = 0.f, a1 = 0.f, a2 = 0.f, a3 = 0.f;
            #pragma unroll
            for (int d = 0; d < 256; d += 16) {
                f32x4 q0 = *(const f32x4*)(q + d);      f32x4 e0 = *(const f32x4*)(e + d);
                f32x4 q1 = *(const f32x4*)(q + d + 4);  f32x4 e1 = *(const f32x4*)(e + d + 4);
                f32x4 q2 = *(const f32x4*)(q + d + 8);  f32x4 e2 = *(const f32x4*)(e + d + 8);
                f32x4 q3 = *(const f32x4*)(q + d + 12); f32x4 e3 = *(const f32x4*)(e + d + 12);
                a0 += q0[0]*e0[0] + q0[1]*e0[1] + q0[2]*e0[2] + q0[3]*e0[3];
                a1 += q1[0]*e1[0] + q1[1]*e1[1] + q1[2]*e1[2] + q1[3]*e1[3];
                a2 += q2[0]*e2[0] + q2[1]*e2[1] + q2[2]*e2[2] + q2[3]*e2[3];
                a3 += q3[0]*e3[0] + q3[1]*e3[1] + q3[2]*e3[2] + q3[3]*e3[3];
            }
            float acc = (a0 + a1) + (a2 + a3);
            acc += __shfl_xor(acc, 1);
            if (part == 0) {
                int key = c * 128 + g * 16 + kr;
                lge[hh * 16 + kr] = (A.pad[b * 2048 + key] != 0.f) ? -2e30f : acc;
            }
        }
        __syncthreads();
        if (tid < 128) {   // online softmax update
            int hh = tid >> 4, k = tid & 15;
            float lv = lge[hh * 16 + k];
            float gm = lv;
            gm = fmaxf(gm, __shfl_xor(gm, 1));
            gm = fmaxf(gm, __shfl_xor(gm, 2));
            gm = fmaxf(gm, __shfl_xor(gm, 4));
            gm = fmaxf(gm, __shfl_xor(gm, 8));
            float mold = mhp[hh];
            float mnew = fmaxf(mold, gm);
            float ev = __expf(lv - mnew);
            float gs = ev;
            gs += __shfl_xor(gs, 1); gs += __shfl_xor(gs, 2);
            gs += __shfl_xor(gs, 4); gs += __shfl_xor(gs, 8);
            float f = __expf(mold - mnew);
            lge[hh * 16 + k] = ev;
            if (k == 0) { shp[hh] = shp[hh] * f + gs; mhp[hh] = mnew; fhp[hh] = f; }
        }
        __syncthreads();
        {   // z accumulation
            float f = fhp[h];
            #pragma unroll
            for (int jj = 0; jj < 4; jj++) z4[jj] *= f;
            #pragma unroll
            for (int k = 0; k < 16; k++) {
                float ev = lge[h * 16 + k];
                #pragma unroll
                for (int jj = 0; jj < 4; jj++) {
                    f32x4 rv = *(const f32x4*)(rows + k * 520 + jj * 128 + ii * 4);
                    z4[jj] += ev * rv;
                }
            }
        }
        __syncthreads();
    }
    int bc = b * 16 + c;
    if (tid < 8) { A.Pm2[bc * 8 + tid] = mhp[tid]; A.Ps2[bc * 8 + tid] = shp[tid]; }
    #pragma unroll
    for (int jj = 0; jj < 4; jj++)
        *(f32x4*)(A.Pz + ((size_t)bc * 8 + h) * 512 + jj * 128 + ii * 4) = z4[jj];
}

// ---------------------------------------------------------------------------

__global__ __launch_bounds__(NTHR, 1) void k_mega(Args A) {
    __shared__ float sm[12700];
    const int bid = blockIdx.x, tid = threadIdx.x;
    const int lane = tid & 63, w = tid >> 6;

    // ---------------- P0: setup (posenc, padflag, enc->bf16) ---------------
    if (bid < 16) {
        int p = bid;
        #pragma unroll
        for (int k = 0; k < 2; k++) {
            int i = tid + k * 256;
            float expo = (2.0f * (float)(i >> 1)) * (1.f / 512.f);
            float f = powf(10000.0f, -expo);
            float ang = (float)p * f;
            A.pos[p * 512 + i] = ((i & 1) == 0) ? sinf(ang) : cosf(ang);
        }
    }
    if (bid < 128) {
        int kg = bid * 256 + tid;          // (b*2048+key)
        const float* p = A.encIn + (size_t)kg * 128;
        int ok = 1;
        for (int i = 0; i < 128; i += 4) {
            float4 v = *(const float4*)(p + i);
            ok &= (v.x == 0.f) & (v.y == 0.f) & (v.z == 0.f) & (v.w == 0.f);
        }
        A.pad[kg] = ok ? 1.f : 0.f;
    } else if (A.encbf) {
        int blk = bid - 128;
        for (int it = 0; it < 128; it++) {
            size_t vi = ((size_t)blk * 128 + it) * 256 + tid;
            float4 v = *(const float4*)(A.enc + vi * 4);
            us4 o; o[0] = f2bf(v.x); o[1] = f2bf(v.y); o[2] = f2bf(v.z); o[3] = f2bf(v.w);
            *(us4*)(A.encbf + vi * 4) = o;
        }
    }
    gsync(A.cnt, A.gen);

    for (int t = 0; t < 16; t++) {
        // ---------------- S_emb ----------------
        if (bid < 32) {
            int cb = bid >> 2, bq = bid & 3;
            int b = bq * 4 + w;
            float* tokw = sm + w * 256;
            #pragma unroll
            for (int i = 0; i < 4; i++)
                tokw[lane + i * 64] = (t == 0) ? 1.f
                    : A.out[(size_t)b * 4096 + (t - 1) * 256 + lane + i * 64];
            __syncthreads();
            int col = cb * 64 + lane;
            float acc = wdot(tokw, A.embW, 256, col, 512) + A.embB[col];
            A.x0[(size_t)b * 512 + col] = acc * 22.627416997969522f + A.pos[t * 512 + col];
        }
        gsync(A.cnt, A.gen);

        for (int l = 0; l < 4; l++) {
            const float* src = (l == 0) ? A.x0 : A.y3;
            const float* gP = (l == 0) ? nullptr : A.lng + ((l - 1) * 3 + 2) * 512;
            const float* bP = (l == 0) ? nullptr : A.lnb + ((l - 1) * 3 + 2) * 512;
            int ulnP = (l != 0);

            // ---------------- S1: self q/k/v projections ----------------
            if (bid < 96) {
                int m = bid >> 5;               // 0=q 1=k 2=v
                int r = bid & 31;
                int cb = r >> 2, bq = r & 3;
                int b = bq * 4 + w;
                float* xsw = sm + w * 512;
                stage_ln_wave(src + (size_t)b * 512, gP, bP, ulnP, xsw, lane);
                __syncthreads();
                int col = cb * 64 + lane;
                const float* W = A.selfW + ((size_t)(l * 4 + m)) * 262144;
                float acc = wdot(xsw, W, 512, col, 512) + A.selfB[(l * 4 + m) * 512 + col];
                if (m == 0) A.qbuf[(size_t)b * 512 + col] = acc;
                else if (m == 1) A.selfK[(((size_t)l * 16 + b) * 16 + t) * 512 + col] = acc;
                else A.selfV[(((size_t)l * 16 + b) * 16 + t) * 512 + col] = acc;
            }
            gsync(A.cnt, A.gen);

            // ---------------- S2: self-attn + output proj (y1 = a + x) ----
            if (bid < 128) {
                int b = bid >> 3, cb = bid & 7;
                float* xr = sm; float* qs = sm + 512; float* as_ = sm + 1024;
                float* lg = sm + 1536; float* wsv = sm + 1664; float* part = sm + 1792;
                float* red = sm + 2056;
                ln512_block(src + (size_t)b * 512, gP, bP, ulnP, xr, red);
                for (int i = tid; i < 512; i += 256) qs[i] = A.qbuf[(size_t)b * 512 + i];
                __syncthreads();
                const float* Kb = A.selfK + ((size_t)l * 16 + b) * 16 * 512;
                const float* Vb = A.selfV + ((size_t)l * 16 + b) * 16 * 512;
                if (tid < 128) {
                    int h = tid >> 4, j = tid & 15;
                    if (j <= t) {
                        const float* kr_ = Kb + (size_t)j * 512 + h * 64;
                        const float* qh_ = qs + h * 64;
                        float s0 = 0.f, s1 = 0.f;
                        #pragma unroll
                        for (int d = 0; d < 64; d += 8) {
                            f32x4 qa = *(const f32x4*)(qh_ + d);
                            f32x4 ka = *(const f32x4*)(kr_ + d);
                            f32x4 qb = *(const f32x4*)(qh_ + d + 4);
                            f32x4 kb = *(const f32x4*)(kr_ + d + 4);
                            s0 += qa[0]*ka[0] + qa[1]*ka[1] + qa[2]*ka[2] + qa[3]*ka[3];
                            s1 += qb[0]*kb[0] + qb[1]*kb[1] + qb[2]*kb[2] + qb[3]*kb[3];
                        }
                        lg[h * 16 + j] = (s0 + s1) * 0.125f;
                    }
                }
                __syncthreads();
                if (tid < 8) {
                    float m = -1e30f;
                    for (int j = 0; j <= t; j++) m = fmaxf(m, lg[tid * 16 + j]);
                    float ssum = 0.f;
                    for (int j = 0; j <= t; j++) {
                        float e = __expf(lg[tid * 16 + j] - m);
                        wsv[tid * 16 + j] = e; ssum += e;
                    }
                    float inv = 1.f / ssum;
                    for (int j = 0; j <= t; j++) wsv[tid * 16 + j] *= inv;
                }
                __syncthreads();
                for (int i = tid; i < 512; i += 256) {
                    int h = i >> 6;
                    float a = 0.f;
                    for (int j = 0; j <= t; j++) a += wsv[h * 16 + j] * Vb[(size_t)j * 512 + i];
                    as_[i] = a;
                }
                __syncthreads();
                const float* Wo = A.selfW + ((size_t)(l * 4 + 3)) * 262144;
                float racc = gemv_splitk(as_, Wo, cb * 64, 512, part);
                if (tid < 64) {
                    int col = cb * 64 + tid;
                    A.y1[(size_t)b * 512 + col] = racc + A.selfB[(l * 4 + 3) * 512 + col] + xr[col];
                }
            }
            gsync(A.cnt, A.gen);

            // ---------------- S3: qc = LN(y1)@Wq_c + bq_c (store lny1) -----
            if (bid < 32) {
                int cb = bid >> 2, bq = bid & 3;
                int b = bq * 4 + w;
                float* xsw = sm + w * 512;
                stage_ln_wave(A.y1 + (size_t)b * 512, A.lng + (l * 3) * 512,
                              A.lnb + (l * 3) * 512, 1, xsw, lane);
                __syncthreads();
                if (cb == 0) {
                    #pragma unroll
                    for (int i = 0; i < 8; i++)
                        A.lny1[(size_t)b * 512 + lane + i * 64] = xsw[lane + i * 64];
                }
                int col = cb * 64 + lane;
                const float* Wq = A.crossW + ((size_t)(l * 4)) * 262144;
                float acc = wdot(xsw, Wq, 512, col, 512) + A.crossB[(l * 4) * 512 + col];
                A.qc[(size_t)b * 512 + col] = acc;
            }
            gsync(A.cnt, A.gen);

            // ---------------- S4: qt[b,h,:] = 0.125 * (qc_h @ Wk_h^T) ------
            if (bid < 128) {
                int b = bid >> 3, h = bid & 7;
                float* qh = sm;
                if (tid < 64) qh[tid] = A.qc[(size_t)b * 512 + h * 64 + tid];
                __syncthreads();
                const float* Wk = A.crossW + ((size_t)(l * 4 + 1)) * 262144;
                #pragma unroll
                for (int pass = 0; pass < 2; pass++) {
                    int D = pass * 256 + tid;
                    const float* wr = Wk + (size_t)D * 512 + h * 64;
                    float a0 = 0.f, a1 = 0.f;
                    #pragma unroll
                    for (int dd = 0; dd < 64; dd += 8) {
                        f32x4 w0 = *(const f32x4*)(wr + dd);
                        f32x4 w1 = *(const f32x4*)(wr + dd + 4);
                        a0 += qh[dd]*w0[0] + qh[dd+1]*w0[1] + qh[dd+2]*w0[2] + qh[dd+3]*w0[3];
                        a1 += qh[dd+4]*w1[0] + qh[dd+5]*w1[1] + qh[dd+6]*w1[2] + qh[dd+7]*w1[3];
                    }
                    A.qt[((size_t)b * 8 + h) * 512 + D] = (a0 + a1) * 0.125f;
                }
            }
            gsync(A.cnt, A.gen);

            // ---------------- S5: flash cross-attn over enc ----------------
            if (A.encbf) flash_stage<1>(A, sm, bid, tid);
            else         flash_stage<0>(A, sm, bid, tid);
            gsync(A.cnt, A.gen);

            // ---------------- S6: combine chunks + @Wv --------------------
            if (bid < 128) {
                int b = bid >> 3, h = bid & 7;
                float* zs = sm; float* part = sm + 1792;
                float mc[16], ec[16];
                float mm = -1e30f;
                #pragma unroll
                for (int cc = 0; cc < 16; cc++) {
                    mc[cc] = A.Pm2[(b * 16 + cc) * 8 + h]; mm = fmaxf(mm, mc[cc]);
                }
                float S = 0.f;
                #pragma unroll
                for (int cc = 0; cc < 16; cc++) {
                    ec[cc] = __expf(mc[cc] - mm);
                    S += ec[cc] * A.Ps2[(b * 16 + cc) * 8 + h];
                }
                float inv = 1.f / S;
                for (int i = tid; i < 512; i += 256) {
                    float a = 0.f;
                    #pragma unroll
                    for (int cc = 0; cc < 16; cc++)
                        a += ec[cc] * A.Pz[((size_t)(b * 16 + cc) * 8 + h) * 512 + i];
                    zs[i] = a * inv;
                }
                __syncthreads();
                const float* Wv = A.crossW + ((size_t)(l * 4 + 2)) * 262144;
                float racc = gemv_splitk(zs, Wv, h * 64, 512, part);
                if (tid < 64)
                    A.attnb[(size_t)b * 512 + h * 64 + tid] =
                        racc + A.crossB[(l * 4 + 2) * 512 + h * 64 + tid];
            }
            gsync(A.cnt, A.gen);

            // ---------------- S7: y2 = attnb@Wo_c + bo_c + lny1 ------------
            if (bid < 32) {
                int cb = bid >> 2, bq = bid & 3;
                int b = bq * 4 + w;
                float* xsw = sm + w * 512;
                #pragma unroll
                for (int i = 0; i < 8; i++)
                    xsw[lane + i * 64] = A.attnb[(size_t)b * 512 + lane + i * 64];
                __syncthreads();
                int col = cb * 64 + lane;
                const float* Wco = A.crossW + ((size_t)(l * 4 + 3)) * 262144;
                float acc = wdot(xsw, Wco, 512, col, 512)
                          + A.crossB[(l * 4 + 3) * 512 + col] + A.lny1[(size_t)b * 512 + col];
                A.y2[(size_t)b * 512 + col] = acc;
            }
            gsync(A.cnt, A.gen);

            // ---------------- S8: ffn1 = relu(LN(y2)@W1+b1) (store lny2) ---
            if (bid < 128) {
                int cb = bid >> 2, bq = bid & 3;   // cb 0..31
                int b = bq * 4 + w;
                float* xsw = sm + w * 512;
                stage_ln_wave(A.y2 + (size_t)b * 512, A.lng + (l * 3 + 1) * 512,
                              A.lnb + (l * 3 + 1) * 512, 1, xsw, lane);
                __syncthreads();
                if (cb == 0) {
                    #pragma unroll
                    for (int i = 0; i < 8; i++)
                        A.lny2[(size_t)b * 512 + lane + i * 64] = xsw[lane + i * 64];
                }
                int col = cb * 64 + lane;
                const float* W1 = A.fW1 + (size_t)l * 512 * 2048;
                float acc = wdot(xsw, W1, 512, col, 2048) + A.fb1[l * 2048 + col];
                A.tmpb[(size_t)b * 2048 + col] = fmaxf(acc, 0.f);
            }
            gsync(A.cnt, A.gen);

            // ---------------- S9a: ffn2 partials (K split 2 x waves 4) -----
            {
                int b = bid >> 4, q = bid & 15;
                int cb = q >> 1, kh = q & 1;
                float* ts = sm; float* part = sm + 1792;
                for (int i = tid; i < 1024; i += 256)
                    ts[i] = A.tmpb[(size_t)b * 2048 + kh * 1024 + i];
                __syncthreads();
                const float* W2 = A.fW2 + (size_t)l * 2048 * 512;
                int col = cb * 64 + lane;
                const float* Wp = W2 + ((size_t)(kh * 1024 + w * 256)) * 512 + col;
                const float* xp = ts + w * 256;
                float a0 = 0.f, a1 = 0.f, a2 = 0.f, a3 = 0.f;
                for (int r = 0; r < 256; r += 4) {
                    a0 += xp[r]     * Wp[(size_t)r * 512];
                    a1 += xp[r + 1] * Wp[(size_t)(r + 1) * 512];
                    a2 += xp[r + 2] * Wp[(size_t)(r + 2) * 512];
                    a3 += xp[r + 3] * Wp[(size_t)(r + 3) * 512];
                }
                part[w * 64 + lane] = (a0 + a1) + (a2 + a3);
                __syncthreads();
                if (tid < 64) {
                    float s = part[tid] + part[64 + tid] + part[128 + tid] + part[192 + tid];
                    A.pf2[((size_t)(kh * 16) + b) * 512 + cb * 64 + tid] = s;
                }
            }
            gsync(A.cnt, A.gen);

            // ---------------- S9b: y3 = pf2[0]+pf2[1]+b2+lny2 --------------
            if (bid < 16) {
                int b = bid;
                for (int i = tid; i < 512; i += 256) {
                    float v = A.pf2[(size_t)b * 512 + i] + A.pf2[((size_t)(16 + b)) * 512 + i]
                            + A.fb2[l * 512 + i] + A.lny2[(size_t)b * 512 + i];
                    A.y3[(size_t)b * 512 + i] = v;
                }
            }
            gsync(A.cnt, A.gen);
        } // l

        // ---------------- S_out: logits for step t ----------------
        if (bid < 16) {
            int cb = bid >> 2, bq = bid & 3;
            int b = bq * 4 + w;
            float* xsw = sm + w * 512;
            stage_ln_wave(A.y3 + (size_t)b * 512, A.lng + 11 * 512, A.lnb + 11 * 512, 1, xsw, lane);
            __syncthreads();
            int col = cb * 64 + lane;
            float acc = wdot(xsw, A.outW, 512, col, 256) + A.outB[col];
            A.out[(size_t)b * 4096 + t * 256 + col] = acc;
        }
        gsync(A.cnt, A.gen);
    } // t
}

// ---------------------------------------------------------------------------

extern "C" void kernel_launch(void* const* d_in, const int* in_sizes, int n_in,
                              void* d_out, int out_size, void* d_ws, size_t ws_size,
                              hipStream_t stream) {
    Args A;
    A.enc    = (const float*)d_in[0];
    A.encIn  = (const float*)d_in[1];
    A.embW   = (const float*)d_in[2];
    A.embB   = (const float*)d_in[3];
    A.outW   = (const float*)d_in[4];
    A.outB   = (const float*)d_in[5];
    A.selfW  = (const float*)d_in[6];
    A.selfB  = (const float*)d_in[7];
    A.crossW = (const float*)d_in[8];
    A.crossB = (const float*)d_in[9];
    A.fW1    = (const float*)d_in[10];
    A.fb1    = (const float*)d_in[11];
    A.fW2    = (const float*)d_in[12];
    A.fb2    = (const float*)d_in[13];
    A.lng    = (const float*)d_in[14];
    A.lnb    = (const float*)d_in[15];
    A.out    = (float*)d_out;

    char* ws = (char*)d_ws;
    size_t off = 0;
    auto alloc = [&](size_t bytes) -> char* {
        char* p = ws + off;
        off = (off + bytes + 255) & ~(size_t)255;
        return p;
    };
    char* barrier = alloc(256);
    A.cnt = (unsigned*)barrier;
    A.gen = (unsigned*)(barrier + 4);
    A.pad   = (float*)alloc((size_t)16 * 2048 * 4);
    A.pos   = (float*)alloc(16 * 512 * 4);
    A.x0    = (float*)alloc(16 * 512 * 4);
    A.qbuf  = (float*)alloc(16 * 512 * 4);
    A.qc    = (float*)alloc(16 * 512 * 4);
    A.y1    = (float*)alloc(16 * 512 * 4);
    A.y2    = (float*)alloc(16 * 512 * 4);
    A.y3    = (float*)alloc(16 * 512 * 4);
    A.attnb = (float*)alloc(16 * 512 * 4);
    A.lny1  = (float*)alloc(16 * 512 * 4);
    A.lny2  = (float*)alloc(16 * 512 * 4);
    A.qt    = (float*)alloc((size_t)16 * 8 * 512 * 4);
    A.Pm2   = (float*)alloc(16 * 16 * 8 * 4);
    A.Ps2   = (float*)alloc(16 * 16 * 8 * 4);
    A.Pz    = (float*)alloc((size_t)16 * 16 * 8 * 512 * 4);
    A.tmpb  = (float*)alloc((size_t)16 * 2048 * 4);
    A.pf2   = (float*)alloc((size_t)2 * 16 * 512 * 4);
    A.selfK = (float*)alloc((size_t)4 * 16 * 16 * 512 * 4);
    A.selfV = (float*)alloc((size_t)4 * 16 * 16 * 512 * 4);
    size_t small_need = off;
    A.encbf = nullptr;
    if (off + (size_t)16 * 2048 * 512 * 2 + 512 <= ws_size)
        A.encbf = (ushort_t*)alloc((size_t)16 * 2048 * 512 * 2);
    if (small_need > ws_size) return;   // ws absurdly small -> zero output

    hipMemsetAsync(barrier, 0, 256, stream);   // barrier counters must be 0
    k_mega<<<dim3(NB), dim3(NTHR), 0, stream>>>(A);
}

// Round 4
// 22230.106 us; speedup vs baseline: 3.6771x; 3.6771x over previous
//
#include <hip/hip_runtime.h>

// ---------------------------------------------------------------------------
// Decoder_49005576847865 — persistent single-kernel incremental decoder.
//   B=16, d=512, H=8 (dh=64), L=4, dff=2048, Lenc=2048, 16 steps, vocab=256.
// Round 4: fix the grid barrier (round 3 spent 99% of time in acquire-ordered
//   agent atomics => per-poll L2 invalidates, ~120us/barrier). New protocol:
//   release fence once -> relaxed monotonic arrive -> relaxed spin on padded
//   release lines -> acquire fence once. Also merged ffn2 partial/combine
//   stages (9 barriers/layer instead of 10).
// ---------------------------------------------------------------------------

typedef unsigned short ushort_t;
typedef __attribute__((ext_vector_type(4))) float f32x4;
typedef __attribute__((ext_vector_type(8))) unsigned short us8;
typedef __attribute__((ext_vector_type(4))) unsigned short us4;

#define NB 256
#define NTHR 256

__device__ __forceinline__ float bf2f(ushort_t u) {
    union { unsigned int i; float f; } v; v.i = ((unsigned int)u) << 16; return v.f;
}
__device__ __forceinline__ ushort_t f2bf(float f) {
    union { unsigned int i; float f; } v; v.f = f;
    return (ushort_t)((v.i + 0x7FFF + ((v.i >> 16) & 1)) >> 16);   // RNE
}
__device__ __forceinline__ float wave_sum(float v) {
    #pragma unroll
    for (int m = 32; m; m >>= 1) v += __shfl_xor(v, m);
    return v;
}

// ---- software grid barrier --------------------------------------------------
// cnt: monotonic arrive counter (never reset during kernel).
// rel: 8 release lines, 128B apart; line i holds "completed epoch count".
// Hot path uses ONLY relaxed atomics (no per-poll cache maintenance);
// exactly one release fence before arrive and one acquire fence after wait.
__device__ __forceinline__ void gsync(unsigned* cnt, unsigned* rel) {
    __syncthreads();
    if (threadIdx.x == 0) {
        __builtin_amdgcn_fence(__ATOMIC_RELEASE, "agent");   // wb my stores
        unsigned a = __hip_atomic_fetch_add(cnt, 1u, __ATOMIC_RELAXED,
                                            __HIP_MEMORY_SCOPE_AGENT);
        unsigned e = a >> 8;                                 // epoch (NB=256)
        if ((a & (NB - 1u)) == NB - 1u) {
            #pragma unroll
            for (int i = 0; i < 8; i++)
                __hip_atomic_store(rel + i * 32, e + 1u, __ATOMIC_RELEASE,
                                   __HIP_MEMORY_SCOPE_AGENT);
        } else {
            unsigned* myrel = rel + (blockIdx.x >> 5) * 32;
            while ((int)(__hip_atomic_load(myrel, __ATOMIC_RELAXED,
                                           __HIP_MEMORY_SCOPE_AGENT) - (e + 1u)) < 0)
                __builtin_amdgcn_s_sleep(4);
        }
        __builtin_amdgcn_fence(__ATOMIC_ACQUIRE, "agent");   // inv stale lines
    }
    __syncthreads();
}

// ---- wave-local LN of one 512 row into smem (no syncs; same-wave use) ------
__device__ __forceinline__ void stage_ln_wave(const float* __restrict__ row,
                                              const float* __restrict__ g,
                                              const float* __restrict__ be,
                                              int use_ln, float* xs, int lane) {
    float loc[8];
    float s = 0.f;
    #pragma unroll
    for (int i = 0; i < 8; i++) { loc[i] = row[lane + i * 64]; s += loc[i]; }
    if (use_ln) {
        s = wave_sum(s);
        float mu = s * (1.f / 512.f);
        float var = 0.f;
        #pragma unroll
        for (int i = 0; i < 8; i++) { float d = loc[i] - mu; var += d * d; }
        var = wave_sum(var);
        float rstd = rsqrtf(var * (1.f / 512.f) + 1e-6f);
        #pragma unroll
        for (int i = 0; i < 8; i++) {
            int c = lane + i * 64;
            xs[c] = (loc[i] - mu) * rstd * g[c] + be[c];
        }
    } else {
        #pragma unroll
        for (int i = 0; i < 8; i++) xs[lane + i * 64] = loc[i];
    }
}

// ---- block-wide LN of one 512 row (256 threads, 2 elems each) --------------
__device__ __forceinline__ void ln512_block(const float* __restrict__ row,
                                            const float* __restrict__ g,
                                            const float* __restrict__ be,
                                            int use_ln, float* dst, float* red) {
    int tid = threadIdx.x;
    float a = row[tid], b = row[tid + 256];
    if (use_ln) {
        float s = wave_sum(a + b);
        if ((tid & 63) == 0) red[tid >> 6] = s;
        __syncthreads();
        float mu = (red[0] + red[1] + red[2] + red[3]) * (1.f / 512.f);
        float d0 = a - mu, d1 = b - mu;
        float v = wave_sum(d0 * d0 + d1 * d1);
        if ((tid & 63) == 0) red[4 + (tid >> 6)] = v;
        __syncthreads();
        float rstd = rsqrtf((red[4] + red[5] + red[6] + red[7]) * (1.f / 512.f) + 1e-6f);
        dst[tid]       = d0 * rstd * g[tid] + be[tid];
        dst[tid + 256] = d1 * rstd * g[tid + 256] + be[tid + 256];
    } else {
        dst[tid] = a; dst[tid + 256] = b;
    }
    __syncthreads();
}

// ---- wave-local dot: 64 cols (lane=col), runtime K, 4 accumulators ---------
__device__ __forceinline__ float wdot(const float* xs, const float* __restrict__ W,
                                      int K, int col, int N) {
    const float* Wp = W + col;
    float a0 = 0.f, a1 = 0.f, a2 = 0.f, a3 = 0.f;
    for (int r = 0; r < K; r += 4) {
        a0 += xs[r]     * Wp[(size_t)r * N];
        a1 += xs[r + 1] * Wp[(size_t)(r + 1) * N];
        a2 += xs[r + 2] * Wp[(size_t)(r + 2) * N];
        a3 += xs[r + 3] * Wp[(size_t)(r + 3) * N];
    }
    return (a0 + a1) + (a2 + a3);
}

// ---- block split-K (K=512, 4 waves x 128 rows); result valid on wave 0 -----
__device__ __forceinline__ float gemv_splitk(const float* xa, const float* __restrict__ W,
                                             int col0, int N, float* part) {
    int lane = threadIdx.x & 63, w = threadIdx.x >> 6;
    const float* Wp = W + ((size_t)(w * 128)) * N + col0 + lane;
    const float* xp = xa + w * 128;
    float a0 = 0.f, a1 = 0.f, a2 = 0.f, a3 = 0.f;
    for (int r = 0; r < 128; r += 4) {
        a0 += xp[r]     * Wp[(size_t)r * N];
        a1 += xp[r + 1] * Wp[(size_t)(r + 1) * N];
        a2 += xp[r + 2] * Wp[(size_t)(r + 2) * N];
        a3 += xp[r + 3] * Wp[(size_t)(r + 3) * N];
    }
    part[w * 64 + lane] = (a0 + a1) + (a2 + a3);
    __syncthreads();
    float r = 0.f;
    if (w == 0) r = part[lane] + part[64 + lane] + part[128 + lane] + part[192 + lane];
    return r;
}

struct Args {
    const float *enc, *encIn, *embW, *embB, *outW, *outB;
    const float *selfW, *selfB, *crossW, *crossB;
    const float *fW1, *fb1, *fW2, *fb2, *lng, *lnb;
    float* out;
    unsigned *cnt, *rel;
    float *pad, *pos, *x0, *qbuf, *qc, *y1, *y2, *y3, *attnb;
    float *lny1, *lny2, *qt, *Pm2, *Ps2, *Pz, *tmpb, *selfK, *selfV;
    ushort_t* encbf;
};

// ---- flash cross-attn stage body (one (b, chunk) per block) ----------------
template<int BF16>
__device__ __forceinline__ void flash_stage(const Args& A, float* sm, int bid, int tid) {
    int b = bid >> 4, c = bid & 15;
    float* qts = sm;            // [8][520]
    float* rows = sm + 4160;    // [16][520]
    float* lge  = sm + 12480;   // [8][16]
    float* mhp  = sm + 12608;
    float* shp  = sm + 12616;
    float* fhp  = sm + 12624;
    for (int i = tid; i < 4096; i += 256)
        qts[(i >> 9) * 520 + (i & 511)] = A.qt[(size_t)b * 4096 + i];
    if (tid < 8) { mhp[tid] = -1e30f; shp[tid] = 0.f; fhp[tid] = 1.f; }
    int h = tid >> 5, ii = tid & 31;
    f32x4 z4[4];
    #pragma unroll
    for (int jj = 0; jj < 4; jj++) z4[jj] = (f32x4){0.f, 0.f, 0.f, 0.f};

    us8 pf[4];
    float4 pf32[8];
    auto LOAD = [&](int g) {
        int key0 = c * 128 + g * 16;
        if (BF16) {
            #pragma unroll
            for (int it = 0; it < 4; it++) {
                int off = it * 2048 + tid * 8;
                int kr = off >> 9, D = off & 511;
                pf[it] = *(const us8*)(A.encbf + ((size_t)b * 2048 + key0 + kr) * 512 + D);
            }
        } else {
            #pragma unroll
            for (int it = 0; it < 8; it++) {
                int off = it * 1024 + tid * 4;
                int kr = off >> 9, D = off & 511;
                pf32[it] = *(const float4*)(A.enc + ((size_t)b * 2048 + key0 + kr) * 512 + D);
            }
        }
    };
    auto STORE = [&]() {
        if (BF16) {
            #pragma unroll
            for (int it = 0; it < 4; it++) {
                int off = it * 2048 + tid * 8;
                int kr = off >> 9, D = off & 511;
                float4 lo = {bf2f(pf[it][0]), bf2f(pf[it][1]), bf2f(pf[it][2]), bf2f(pf[it][3])};
                float4 hi = {bf2f(pf[it][4]), bf2f(pf[it][5]), bf2f(pf[it][6]), bf2f(pf[it][7])};
                *(float4*)(rows + kr * 520 + D)     = lo;
                *(float4*)(rows + kr * 520 + D + 4) = hi;
            }
        } else {
            #pragma unroll
            for (int it = 0; it < 8; it++) {
                int off = it * 1024 + tid * 4;
                int kr = off >> 9, D = off & 511;
                *(float4*)(rows + kr * 520 + D) = pf32[it];
            }
        }
    };

    LOAD(0);
    __syncthreads();   // qts staged
    for (int g = 0; g < 8; g++) {
        STORE();
        if (g < 7) LOAD(g + 1);
        __syncthreads();
        {   // logits: 16 keys x 8 heads, 2-way K split
            int kr = tid >> 4, hh = (tid >> 1) & 7, part = tid & 1;
            const float* q = qts + hh * 520 + part * 256;
            const float* e = rows + kr * 520 + part * 256;
            float a0 = 0.f, a1 = 0.f, a2 = 0.f, a3 = 0.f;
            #pragma unroll
            for (int d = 0; d < 256; d += 16) {
                f32x4 q0 = *(const f32x4*)(q + d);      f32x4 e0 = *(const f32x4*)(e + d);
                f32x4 q1 = *(const f32x4*)(q + d + 4);  f32x4 e1 = *(const f32x4*)(e + d + 4);
                f32x4 q2 = *(const f32x4*)(q + d + 8);  f32x4 e2 = *(const f32x4*)(e + d + 8);
                f32x4 q3 = *(const f32x4*)(q + d + 12); f32x4 e3 = *(const f32x4*)(e + d + 12);
                a0 += q0[0]*e0[0] + q0[1]*e0[1] + q0[2]*e0[2] + q0[3]*e0[3];
                a1 += q1[0]*e1[0] + q1[1]*e1[1] + q1[2]*e1[2] + q1[3]*e1[3];
                a2 += q2[0]*e2[0] + q2[1]*e2[1] + q2[2]*e2[2] + q2[3]*e2[3];
                a3 += q3[0]*e3[0] + q3[1]*e3[1] + q3[2]*e3[2] + q3[3]*e3[3];
            }
            float acc = (a0 + a1) + (a2 + a3);
            acc += __shfl_xor(acc, 1);
            if (part == 0) {
                int key = c * 128 + g * 16 + kr;
                lge[hh * 16 + kr] = (A.pad[b * 2048 + key] != 0.f) ? -2e30f : acc;
            }
        }
        __syncthreads();
        if (tid < 128) {   // online softmax update
            int hh = tid >> 4, k = tid & 15;
            float lv = lge[hh * 16 + k];
            float gm = lv;
            gm = fmaxf(gm, __shfl_xor(gm, 1));
            gm = fmaxf(gm, __shfl_xor(gm, 2));
            gm = fmaxf(gm, __shfl_xor(gm, 4));
            gm = fmaxf(gm, __shfl_xor(gm, 8));
            float mold = mhp[hh];
            float mnew = fmaxf(mold, gm);
            float ev = __expf(lv - mnew);
            float gs = ev;
            gs += __shfl_xor(gs, 1); gs += __shfl_xor(gs, 2);
            gs += __shfl_xor(gs, 4); gs += __shfl_xor(gs, 8);
            float f = __expf(mold - mnew);
            lge[hh * 16 + k] = ev;
            if (k == 0) { shp[hh] = shp[hh] * f + gs; mhp[hh] = mnew; fhp[hh] = f; }
        }
        __syncthreads();
        {   // z accumulation
            float f = fhp[h];
            #pragma unroll
            for (int jj = 0; jj < 4; jj++) z4[jj] *= f;
            #pragma unroll
            for (int k = 0; k < 16; k++) {
                float ev = lge[h * 16 + k];
                #pragma unroll
                for (int jj = 0; jj < 4; jj++) {
                    f32x4 rv = *(const f32x4*)(rows + k * 520 + jj * 128 + ii * 4);
                    z4[jj] += ev * rv;
                }
            }
        }
        __syncthreads();
    }
    int bc = b * 16 + c;
    if (tid < 8) { A.Pm2[bc * 8 + tid] = mhp[tid]; A.Ps2[bc * 8 + tid] = shp[tid]; }
    #pragma unroll
    for (int jj = 0; jj < 4; jj++)
        *(f32x4*)(A.Pz + ((size_t)bc * 8 + h) * 512 + jj * 128 + ii * 4) = z4[jj];
}

// ---------------------------------------------------------------------------

__global__ __launch_bounds__(NTHR, 1) void k_mega(Args A) {
    __shared__ float sm[12700];
    const int bid = blockIdx.x, tid = threadIdx.x;
    const int lane = tid & 63, w = tid >> 6;

    // ---------------- P0: setup (posenc, padflag, enc->bf16) ---------------
    if (bid < 16) {
        int p = bid;
        #pragma unroll
        for (int k = 0; k < 2; k++) {
            int i = tid + k * 256;
            float expo = (2.0f * (float)(i >> 1)) * (1.f / 512.f);
            float f = powf(10000.0f, -expo);
            float ang = (float)p * f;
            A.pos[p * 512 + i] = ((i & 1) == 0) ? sinf(ang) : cosf(ang);
        }
    }
    if (bid < 128) {
        int kg = bid * 256 + tid;          // (b*2048+key)
        const float* p = A.encIn + (size_t)kg * 128;
        int ok = 1;
        for (int i = 0; i < 128; i += 4) {
            float4 v = *(const float4*)(p + i);
            ok &= (v.x == 0.f) & (v.y == 0.f) & (v.z == 0.f) & (v.w == 0.f);
        }
        A.pad[kg] = ok ? 1.f : 0.f;
    } else if (A.encbf) {
        int blk = bid - 128;
        for (int it = 0; it < 128; it++) {
            size_t vi = ((size_t)blk * 128 + it) * 256 + tid;
            float4 v = *(const float4*)(A.enc + vi * 4);
            us4 o; o[0] = f2bf(v.x); o[1] = f2bf(v.y); o[2] = f2bf(v.z); o[3] = f2bf(v.w);
            *(us4*)(A.encbf + vi * 4) = o;
        }
    }
    gsync(A.cnt, A.rel);

    for (int t = 0; t < 16; t++) {
        // ---------------- S_emb ----------------
        if (bid < 32) {
            int cb = bid >> 2, bq = bid & 3;
            int b = bq * 4 + w;
            float* tokw = sm + w * 256;
            #pragma unroll
            for (int i = 0; i < 4; i++)
                tokw[lane + i * 64] = (t == 0) ? 1.f
                    : A.out[(size_t)b * 4096 + (t - 1) * 256 + lane + i * 64];
            __syncthreads();
            int col = cb * 64 + lane;
            float acc = wdot(tokw, A.embW, 256, col, 512) + A.embB[col];
            A.x0[(size_t)b * 512 + col] = acc * 22.627416997969522f + A.pos[t * 512 + col];
        }
        gsync(A.cnt, A.rel);

        for (int l = 0; l < 4; l++) {
            const float* src = (l == 0) ? A.x0 : A.y3;
            const float* gP = (l == 0) ? nullptr : A.lng + ((l - 1) * 3 + 2) * 512;
            const float* bP = (l == 0) ? nullptr : A.lnb + ((l - 1) * 3 + 2) * 512;
            int ulnP = (l != 0);

            // ---------------- S1: self q/k/v projections ----------------
            if (bid < 96) {
                int m = bid >> 5;               // 0=q 1=k 2=v
                int r = bid & 31;
                int cb = r >> 2, bq = r & 3;
                int b = bq * 4 + w;
                float* xsw = sm + w * 512;
                stage_ln_wave(src + (size_t)b * 512, gP, bP, ulnP, xsw, lane);
                __syncthreads();
                int col = cb * 64 + lane;
                const float* W = A.selfW + ((size_t)(l * 4 + m)) * 262144;
                float acc = wdot(xsw, W, 512, col, 512) + A.selfB[(l * 4 + m) * 512 + col];
                if (m == 0) A.qbuf[(size_t)b * 512 + col] = acc;
                else if (m == 1) A.selfK[(((size_t)l * 16 + b) * 16 + t) * 512 + col] = acc;
                else A.selfV[(((size_t)l * 16 + b) * 16 + t) * 512 + col] = acc;
            }
            gsync(A.cnt, A.rel);

            // ---------------- S2: self-attn + output proj (y1 = a + x) ----
            if (bid < 128) {
                int b = bid >> 3, cb = bid & 7;
                float* xr = sm; float* qs = sm + 512; float* as_ = sm + 1024;
                float* lg = sm + 1536; float* wsv = sm + 1664; float* part = sm + 1792;
                float* red = sm + 2056;
                ln512_block(src + (size_t)b * 512, gP, bP, ulnP, xr, red);
                for (int i = tid; i < 512; i += 256) qs[i] = A.qbuf[(size_t)b * 512 + i];
                __syncthreads();
                const float* Kb = A.selfK + ((size_t)l * 16 + b) * 16 * 512;
                const float* Vb = A.selfV + ((size_t)l * 16 + b) * 16 * 512;
                if (tid < 128) {
                    int h = tid >> 4, j = tid & 15;
                    if (j <= t) {
                        const float* kr_ = Kb + (size_t)j * 512 + h * 64;
                        const float* qh_ = qs + h * 64;
                        float s0 = 0.f, s1 = 0.f;
                        #pragma unroll
                        for (int d = 0; d < 64; d += 8) {
                            f32x4 qa = *(const f32x4*)(qh_ + d);
                            f32x4 ka = *(const f32x4*)(kr_ + d);
                            f32x4 qb = *(const f32x4*)(qh_ + d + 4);
                            f32x4 kb = *(const f32x4*)(kr_ + d + 4);
                            s0 += qa[0]*ka[0] + qa[1]*ka[1] + qa[2]*ka[2] + qa[3]*ka[3];
                            s1 += qb[0]*kb[0] + qb[1]*kb[1] + qb[2]*kb[2] + qb[3]*kb[3];
                        }
                        lg[h * 16 + j] = (s0 + s1) * 0.125f;
                    }
                }
                __syncthreads();
                if (tid < 8) {
                    float m = -1e30f;
                    for (int j = 0; j <= t; j++) m = fmaxf(m, lg[tid * 16 + j]);
                    float ssum = 0.f;
                    for (int j = 0; j <= t; j++) {
                        float e = __expf(lg[tid * 16 + j] - m);
                        wsv[tid * 16 + j] = e; ssum += e;
                    }
                    float inv = 1.f / ssum;
                    for (int j = 0; j <= t; j++) wsv[tid * 16 + j] *= inv;
                }
                __syncthreads();
                for (int i = tid; i < 512; i += 256) {
                    int h = i >> 6;
                    float a = 0.f;
                    for (int j = 0; j <= t; j++) a += wsv[h * 16 + j] * Vb[(size_t)j * 512 + i];
                    as_[i] = a;
                }
                __syncthreads();
                const float* Wo = A.selfW + ((size_t)(l * 4 + 3)) * 262144;
                float racc = gemv_splitk(as_, Wo, cb * 64, 512, part);
                if (tid < 64) {
                    int col = cb * 64 + tid;
                    A.y1[(size_t)b * 512 + col] = racc + A.selfB[(l * 4 + 3) * 512 + col] + xr[col];
                }
            }
            gsync(A.cnt, A.rel);

            // ---------------- S3: qc = LN(y1)@Wq_c + bq_c (store lny1) -----
            if (bid < 32) {
                int cb = bid >> 2, bq = bid & 3;
                int b = bq * 4 + w;
                float* xsw = sm + w * 512;
                stage_ln_wave(A.y1 + (size_t)b * 512, A.lng + (l * 3) * 512,
                              A.lnb + (l * 3) * 512, 1, xsw, lane);
                __syncthreads();
                if (cb == 0) {
                    #pragma unroll
                    for (int i = 0; i < 8; i++)
                        A.lny1[(size_t)b * 512 + lane + i * 64] = xsw[lane + i * 64];
                }
                int col = cb * 64 + lane;
                const float* Wq = A.crossW + ((size_t)(l * 4)) * 262144;
                float acc = wdot(xsw, Wq, 512, col, 512) + A.crossB[(l * 4) * 512 + col];
                A.qc[(size_t)b * 512 + col] = acc;
            }
            gsync(A.cnt, A.rel);

            // ---------------- S4: qt[b,h,:] = 0.125 * (qc_h @ Wk_h^T) ------
            if (bid < 128) {
                int b = bid >> 3, h = bid & 7;
                float* qh = sm;
                if (tid < 64) qh[tid] = A.qc[(size_t)b * 512 + h * 64 + tid];
                __syncthreads();
                const float* Wk = A.crossW + ((size_t)(l * 4 + 1)) * 262144;
                #pragma unroll
                for (int pass = 0; pass < 2; pass++) {
                    int D = pass * 256 + tid;
                    const float* wr = Wk + (size_t)D * 512 + h * 64;
                    float a0 = 0.f, a1 = 0.f;
                    #pragma unroll
                    for (int dd = 0; dd < 64; dd += 8) {
                        f32x4 w0 = *(const f32x4*)(wr + dd);
                        f32x4 w1 = *(const f32x4*)(wr + dd + 4);
                        a0 += qh[dd]*w0[0] + qh[dd+1]*w0[1] + qh[dd+2]*w0[2] + qh[dd+3]*w0[3];
                        a1 += qh[dd+4]*w1[0] + qh[dd+5]*w1[1] + qh[dd+6]*w1[2] + qh[dd+7]*w1[3];
                    }
                    A.qt[((size_t)b * 8 + h) * 512 + D] = (a0 + a1) * 0.125f;
                }
            }
            gsync(A.cnt, A.rel);

            // ---------------- S5: flash cross-attn over enc ----------------
            if (A.encbf) flash_stage<1>(A, sm, bid, tid);
            else         flash_stage<0>(A, sm, bid, tid);
            gsync(A.cnt, A.rel);

            // ---------------- S6: combine chunks + @Wv --------------------
            if (bid < 128) {
                int b = bid >> 3, h = bid & 7;
                float* zs = sm; float* part = sm + 1792;
                float mc[16], ec[16];
                float mm = -1e30f;
                #pragma unroll
                for (int cc = 0; cc < 16; cc++) {
                    mc[cc] = A.Pm2[(b * 16 + cc) * 8 + h]; mm = fmaxf(mm, mc[cc]);
                }
                float S = 0.f;
                #pragma unroll
                for (int cc = 0; cc < 16; cc++) {
                    ec[cc] = __expf(mc[cc] - mm);
                    S += ec[cc] * A.Ps2[(b * 16 + cc) * 8 + h];
                }
                float inv = 1.f / S;
                for (int i = tid; i < 512; i += 256) {
                    float a = 0.f;
                    #pragma unroll
                    for (int cc = 0; cc < 16; cc++)
                        a += ec[cc] * A.Pz[((size_t)(b * 16 + cc) * 8 + h) * 512 + i];
                    zs[i] = a * inv;
                }
                __syncthreads();
                const float* Wv = A.crossW + ((size_t)(l * 4 + 2)) * 262144;
                float racc = gemv_splitk(zs, Wv, h * 64, 512, part);
                if (tid < 64)
                    A.attnb[(size_t)b * 512 + h * 64 + tid] =
                        racc + A.crossB[(l * 4 + 2) * 512 + h * 64 + tid];
            }
            gsync(A.cnt, A.rel);

            // ---------------- S7: y2 = attnb@Wo_c + bo_c + lny1 ------------
            if (bid < 32) {
                int cb = bid >> 2, bq = bid & 3;
                int b = bq * 4 + w;
                float* xsw = sm + w * 512;
                #pragma unroll
                for (int i = 0; i < 8; i++)
                    xsw[lane + i * 64] = A.attnb[(size_t)b * 512 + lane + i * 64];
                __syncthreads();
                int col = cb * 64 + lane;
                const float* Wco = A.crossW + ((size_t)(l * 4 + 3)) * 262144;
                float acc = wdot(xsw, Wco, 512, col, 512)
                          + A.crossB[(l * 4 + 3) * 512 + col] + A.lny1[(size_t)b * 512 + col];
                A.y2[(size_t)b * 512 + col] = acc;
            }
            gsync(A.cnt, A.rel);

            // ---------------- S8: ffn1 = relu(LN(y2)@W1+b1) (store lny2) ---
            if (bid < 128) {
                int cb = bid >> 2, bq = bid & 3;   // cb 0..31
                int b = bq * 4 + w;
                float* xsw = sm + w * 512;
                stage_ln_wave(A.y2 + (size_t)b * 512, A.lng + (l * 3 + 1) * 512,
                              A.lnb + (l * 3 + 1) * 512, 1, xsw, lane);
                __syncthreads();
                if (cb == 0) {
                    #pragma unroll
                    for (int i = 0; i < 8; i++)
                        A.lny2[(size_t)b * 512 + lane + i * 64] = xsw[lane + i * 64];
                }
                int col = cb * 64 + lane;
                const float* W1 = A.fW1 + (size_t)l * 512 * 2048;
                float acc = wdot(xsw, W1, 512, col, 2048) + A.fb1[l * 2048 + col];
                A.tmpb[(size_t)b * 2048 + col] = fmaxf(acc, 0.f);
            }
            gsync(A.cnt, A.rel);

            // ---------------- S9: y3 = tmpb@W2 + b2 + lny2 (split-K=2048) --
            if (bid < 128) {
                int b = bid >> 3, cb = bid & 7;
                float* ts = sm;            // 2048
                float* part = sm + 2048;   // 256
                for (int i = tid; i < 2048; i += 256)
                    ts[i] = A.tmpb[(size_t)b * 2048 + i];
                __syncthreads();
                const float* W2 = A.fW2 + (size_t)l * 2048 * 512;
                int col = cb * 64 + lane;
                const float* Wp = W2 + ((size_t)(w * 512)) * 512 + col;
                const float* xp = ts + w * 512;
                float a0 = 0.f, a1 = 0.f, a2 = 0.f, a3 = 0.f;
                for (int r = 0; r < 512; r += 4) {
                    a0 += xp[r]     * Wp[(size_t)r * 512];
                    a1 += xp[r + 1] * Wp[(size_t)(r + 1) * 512];
                    a2 += xp[r + 2] * Wp[(size_t)(r + 2) * 512];
                    a3 += xp[r + 3] * Wp[(size_t)(r + 3) * 512];
                }
                part[w * 64 + lane] = (a0 + a1) + (a2 + a3);
                __syncthreads();
                if (tid < 64) {
                    float s = part[tid] + part[64 + tid] + part[128 + tid] + part[192 + tid];
                    int c2 = cb * 64 + tid;
                    A.y3[(size_t)b * 512 + c2] = s + A.fb2[l * 512 + c2]
                                               + A.lny2[(size_t)b * 512 + c2];
                }
            }
            gsync(A.cnt, A.rel);
        } // l

        // ---------------- S_out: logits for step t ----------------
        if (bid < 16) {
            int cb = bid >> 2, bq = bid & 3;
            int b = bq * 4 + w;
            float* xsw = sm + w * 512;
            stage_ln_wave(A.y3 + (size_t)b * 512, A.lng + 11 * 512, A.lnb + 11 * 512, 1, xsw, lane);
            __syncthreads();
            int col = cb * 64 + lane;
            float acc = wdot(xsw, A.outW, 512, col, 256) + A.outB[col];
            A.out[(size_t)b * 4096 + t * 256 + col] = acc;
        }
        gsync(A.cnt, A.rel);
    } // t
}

// ---------------------------------------------------------------------------

extern "C" void kernel_launch(void* const* d_in, const int* in_sizes, int n_in,
                              void* d_out, int out_size, void* d_ws, size_t ws_size,
                              hipStream_t stream) {
    Args A;
    A.enc    = (const float*)d_in[0];
    A.encIn  = (const float*)d_in[1];
    A.embW   = (const float*)d_in[2];
    A.embB   = (const float*)d_in[3];
    A.outW   = (const float*)d_in[4];
    A.outB   = (const float*)d_in[5];
    A.selfW  = (const float*)d_in[6];
    A.selfB  = (const float*)d_in[7];
    A.crossW = (const float*)d_in[8];
    A.crossB = (const float*)d_in[9];
    A.fW1    = (const float*)d_in[10];
    A.fb1    = (const float*)d_in[11];
    A.fW2    = (const float*)d_in[12];
    A.fb2    = (const float*)d_in[13];
    A.lng    = (const float*)d_in[14];
    A.lnb    = (const float*)d_in[15];
    A.out    = (float*)d_out;

    char* ws = (char*)d_ws;
    size_t off = 0;
    auto alloc = [&](size_t bytes) -> char* {
        char* p = ws + off;
        off = (off + bytes + 255) & ~(size_t)255;
        return p;
    };
    char* barrier = alloc(2048);
    A.cnt = (unsigned*)barrier;            // monotonic arrive counter
    A.rel = (unsigned*)(barrier + 128);    // 8 release lines, 128B apart
    A.pad   = (float*)alloc((size_t)16 * 2048 * 4);
    A.pos   = (float*)alloc(16 * 512 * 4);
    A.x0    = (float*)alloc(16 * 512 * 4);
    A.qbuf  = (float*)alloc(16 * 512 * 4);
    A.qc    = (float*)alloc(16 * 512 * 4);
    A.y1    = (float*)alloc(16 * 512 * 4);
    A.y2    = (float*)alloc(16 * 512 * 4);
    A.y3    = (float*)alloc(16 * 512 * 4);
    A.attnb = (float*)alloc(16 * 512 * 4);
    A.lny1  = (float*)alloc(16 * 512 * 4);
    A.lny2  = (float*)alloc(16 * 512 * 4);
    A.qt    = (float*)alloc((size_t)16 * 8 * 512 * 4);
    A.Pm2   = (float*)alloc(16 * 16 * 8 * 4);
    A.Ps2   = (float*)alloc(16 * 16 * 8 * 4);
    A.Pz    = (float*)alloc((size_t)16 * 16 * 8 * 512 * 4);
    A.tmpb  = (float*)alloc((size_t)16 * 2048 * 4);
    A.selfK = (float*)alloc((size_t)4 * 16 * 16 * 512 * 4);
    A.selfV = (float*)alloc((size_t)4 * 16 * 16 * 512 * 4);
    size_t small_need = off;
    A.encbf = nullptr;
    if (off + (size_t)16 * 2048 * 512 * 2 + 512 <= ws_size)
        A.encbf = (ushort_t*)alloc((size_t)16 * 2048 * 512 * 2);
    if (small_need > ws_size) return;   // ws absurdly small -> zero output

    hipMemsetAsync(barrier, 0, 2048, stream);   // barrier state must start at 0
    k_mega<<<dim3(NB), dim3(NTHR), 0, stream>>>(A);
}

// Round 5
// 20696.759 us; speedup vs baseline: 3.9495x; 1.0741x over previous
//
#include <hip/hip_runtime.h>

// ---------------------------------------------------------------------------
// Decoder_49005576847865 — persistent single-kernel incremental decoder.
//   B=16, d=512, H=8 (dh=64), L=4, dff=2048, Lenc=2048, 16 steps, vocab=256.
// Round 5: FENCE-FREE grid barrier. Round 4 spent ~20ms in agent fences
//   (full L2 wb/inv per block per barrier => 3GB HBM refetch). Now:
//   * activation buffers accessed ONLY via agent-scope relaxed atomics
//     (per-access cross-XCD coherent, no cache maintenance),
//   * weights/enc read with normal cached loads (read-only => never stale,
//     stay L2/L3-hot the whole kernel),
//   * barrier = two-level relaxed-atomic arrive tree, zero fences.
// ---------------------------------------------------------------------------

typedef unsigned short ushort_t;
typedef __attribute__((ext_vector_type(4))) float f32x4;
typedef __attribute__((ext_vector_type(8))) unsigned short us8;
typedef __attribute__((ext_vector_type(4))) unsigned short us4;

#define NB 256
#define NTHR 256

__device__ __forceinline__ float bf2f(ushort_t u) {
    union { unsigned int i; float f; } v; v.i = ((unsigned int)u) << 16; return v.f;
}
__device__ __forceinline__ ushort_t f2bf(float f) {
    union { unsigned int i; float f; } v; v.f = f;
    return (ushort_t)((v.i + 0x7FFF + ((v.i >> 16) & 1)) >> 16);   // RNE
}
__device__ __forceinline__ float wave_sum(float v) {
    #pragma unroll
    for (int m = 32; m; m >>= 1) v += __shfl_xor(v, m);
    return v;
}

// ---- coherent (agent-scope, fence-free) workspace access -------------------
union U64C { unsigned long long u; float2 f; us4 s4; };
__device__ __forceinline__ float clf(const float* p) {
    return __hip_atomic_load(p, __ATOMIC_RELAXED, __HIP_MEMORY_SCOPE_AGENT);
}
__device__ __forceinline__ void csf(float* p, float v) {
    __hip_atomic_store(p, v, __ATOMIC_RELAXED, __HIP_MEMORY_SCOPE_AGENT);
}
__device__ __forceinline__ float2 clf2(const float* p) {
    U64C c; c.u = __hip_atomic_load((unsigned long long*)p, __ATOMIC_RELAXED,
                                    __HIP_MEMORY_SCOPE_AGENT);
    return c.f;
}
__device__ __forceinline__ void csf2(float* p, float x, float y) {
    U64C c; c.f.x = x; c.f.y = y;
    __hip_atomic_store((unsigned long long*)p, c.u, __ATOMIC_RELAXED,
                       __HIP_MEMORY_SCOPE_AGENT);
}
__device__ __forceinline__ us4 clu4(const ushort_t* p) {
    U64C c; c.u = __hip_atomic_load((unsigned long long*)p, __ATOMIC_RELAXED,
                                    __HIP_MEMORY_SCOPE_AGENT);
    return c.s4;
}
__device__ __forceinline__ void csu4(ushort_t* p, us4 v) {
    U64C c; c.s4 = v;
    __hip_atomic_store((unsigned long long*)p, c.u, __ATOMIC_RELAXED,
                       __HIP_MEMORY_SCOPE_AGENT);
}

// ---- fence-free grid barrier -----------------------------------------------
// Layout (u32 indices into bar): [0]=master, [32..32*8]=8 sub lines (128B
// apart), [32*9..]=8 release lines. All relaxed agent atomics; __syncthreads
// drains vmcnt(0) so each block's coherent stores are at the MALL before it
// arrives. No fences => no L2 wb/inv ever.
__device__ __forceinline__ void gsync(unsigned* bar) {
    __syncthreads();
    if (threadIdx.x == 0) {
        unsigned grp = blockIdx.x & 7u;
        unsigned* sub = bar + 32 + grp * 32;
        unsigned* rel = bar + 32 * 9;
        unsigned s = __hip_atomic_fetch_add(sub, 1u, __ATOMIC_RELAXED,
                                            __HIP_MEMORY_SCOPE_AGENT);
        unsigned e = s >> 5;                 // 32 blocks per sub-group
        bool fin = false;
        if ((s & 31u) == 31u) {              // last of my group
            unsigned a = __hip_atomic_fetch_add(bar, 1u, __ATOMIC_RELAXED,
                                                __HIP_MEMORY_SCOPE_AGENT);
            if ((a & 7u) == 7u) {            // last group overall
                #pragma unroll
                for (int i = 0; i < 8; i++)
                    __hip_atomic_store(rel + i * 32, e + 1u, __ATOMIC_RELAXED,
                                       __HIP_MEMORY_SCOPE_AGENT);
                fin = true;
            }
        }
        if (!fin) {
            unsigned* myrel = rel + grp * 32;
            while ((int)(__hip_atomic_load(myrel, __ATOMIC_RELAXED,
                                           __HIP_MEMORY_SCOPE_AGENT) - (e + 1u)) < 0)
                __builtin_amdgcn_s_sleep(2);
        }
    }
    __syncthreads();
}

// ---- wave-local LN of one 512 row (coherent loads) into smem ---------------
__device__ __forceinline__ void stage_ln_wave(const float* __restrict__ row,
                                              const float* __restrict__ g,
                                              const float* __restrict__ be,
                                              int use_ln, float* xs, int lane) {
    float loc[8];
    float s = 0.f;
    #pragma unroll
    for (int i = 0; i < 8; i++) { loc[i] = clf(row + lane + i * 64); s += loc[i]; }
    if (use_ln) {
        s = wave_sum(s);
        float mu = s * (1.f / 512.f);
        float var = 0.f;
        #pragma unroll
        for (int i = 0; i < 8; i++) { float d = loc[i] - mu; var += d * d; }
        var = wave_sum(var);
        float rstd = rsqrtf(var * (1.f / 512.f) + 1e-6f);
        #pragma unroll
        for (int i = 0; i < 8; i++) {
            int c = lane + i * 64;
            xs[c] = (loc[i] - mu) * rstd * g[c] + be[c];
        }
    } else {
        #pragma unroll
        for (int i = 0; i < 8; i++) xs[lane + i * 64] = loc[i];
    }
}

// ---- block-wide LN of one 512 row (256 threads, coherent loads) ------------
__device__ __forceinline__ void ln512_block(const float* __restrict__ row,
                                            const float* __restrict__ g,
                                            const float* __restrict__ be,
                                            int use_ln, float* dst, float* red) {
    int tid = threadIdx.x;
    float a = clf(row + tid), b = clf(row + tid + 256);
    if (use_ln) {
        float s = wave_sum(a + b);
        if ((tid & 63) == 0) red[tid >> 6] = s;
        __syncthreads();
        float mu = (red[0] + red[1] + red[2] + red[3]) * (1.f / 512.f);
        float d0 = a - mu, d1 = b - mu;
        float v = wave_sum(d0 * d0 + d1 * d1);
        if ((tid & 63) == 0) red[4 + (tid >> 6)] = v;
        __syncthreads();
        float rstd = rsqrtf((red[4] + red[5] + red[6] + red[7]) * (1.f / 512.f) + 1e-6f);
        dst[tid]       = d0 * rstd * g[tid] + be[tid];
        dst[tid + 256] = d1 * rstd * g[tid + 256] + be[tid + 256];
    } else {
        dst[tid] = a; dst[tid + 256] = b;
    }
    __syncthreads();
}

// ---- wave-local dot: 64 cols (lane=col), runtime K, 4 accumulators ---------
__device__ __forceinline__ float wdot(const float* xs, const float* __restrict__ W,
                                      int K, int col, int N) {
    const float* Wp = W + col;
    float a0 = 0.f, a1 = 0.f, a2 = 0.f, a3 = 0.f;
    for (int r = 0; r < K; r += 4) {
        a0 += xs[r]     * Wp[(size_t)r * N];
        a1 += xs[r + 1] * Wp[(size_t)(r + 1) * N];
        a2 += xs[r + 2] * Wp[(size_t)(r + 2) * N];
        a3 += xs[r + 3] * Wp[(size_t)(r + 3) * N];
    }
    return (a0 + a1) + (a2 + a3);
}

// ---- block split-K (K=512, 4 waves x 128 rows); result valid on wave 0 -----
__device__ __forceinline__ float gemv_splitk(const float* xa, const float* __restrict__ W,
                                             int col0, int N, float* part) {
    int lane = threadIdx.x & 63, w = threadIdx.x >> 6;
    const float* Wp = W + ((size_t)(w * 128)) * N + col0 + lane;
    const float* xp = xa + w * 128;
    float a0 = 0.f, a1 = 0.f, a2 = 0.f, a3 = 0.f;
    for (int r = 0; r < 128; r += 4) {
        a0 += xp[r]     * Wp[(size_t)r * N];
        a1 += xp[r + 1] * Wp[(size_t)(r + 1) * N];
        a2 += xp[r + 2] * Wp[(size_t)(r + 2) * N];
        a3 += xp[r + 3] * Wp[(size_t)(r + 3) * N];
    }
    part[w * 64 + lane] = (a0 + a1) + (a2 + a3);
    __syncthreads();
    float r = 0.f;
    if (w == 0) r = part[lane] + part[64 + lane] + part[128 + lane] + part[192 + lane];
    return r;
}

struct Args {
    const float *enc, *encIn, *embW, *embB, *outW, *outB;
    const float *selfW, *selfB, *crossW, *crossB;
    const float *fW1, *fb1, *fW2, *fb2, *lng, *lnb;
    float* out;
    unsigned* bar;
    float *pad, *pos, *x0, *qbuf, *qc, *y1, *y2, *y3, *attnb;
    float *lny1, *lny2, *qt, *Pm2, *Ps2, *Pz, *tmpb, *selfK, *selfV;
    ushort_t* encbf;
};

// ---- flash cross-attn stage body (one (b, chunk) per block) ----------------
template<int BF16>
__device__ __forceinline__ void flash_stage(const Args& A, float* sm, int bid, int tid) {
    int b = bid >> 4, c = bid & 15;
    float* qts = sm;            // [8][520]
    float* rows = sm + 4160;    // [16][520]
    float* lge  = sm + 12480;   // [8][16]
    float* mhp  = sm + 12608;
    float* shp  = sm + 12616;
    float* fhp  = sm + 12624;
    for (int i = tid; i < 4096; i += 256)
        qts[(i >> 9) * 520 + (i & 511)] = clf(A.qt + (size_t)b * 4096 + i);
    if (tid < 8) { mhp[tid] = -1e30f; shp[tid] = 0.f; fhp[tid] = 1.f; }
    int h = tid >> 5, ii = tid & 31;
    f32x4 z4[4];
    #pragma unroll
    for (int jj = 0; jj < 4; jj++) z4[jj] = (f32x4){0.f, 0.f, 0.f, 0.f};

    us4 pf4[8];
    float4 pf32[8];
    auto LOAD = [&](int g) {
        int key0 = c * 128 + g * 16;
        if (BF16) {
            #pragma unroll
            for (int it = 0; it < 4; it++) {
                int off = it * 2048 + tid * 8;
                int kr = off >> 9, D = off & 511;
                const ushort_t* src = A.encbf + ((size_t)b * 2048 + key0 + kr) * 512 + D;
                pf4[it * 2]     = clu4(src);
                pf4[it * 2 + 1] = clu4(src + 4);
            }
        } else {
            #pragma unroll
            for (int it = 0; it < 8; it++) {
                int off = it * 1024 + tid * 4;
                int kr = off >> 9, D = off & 511;
                pf32[it] = *(const float4*)(A.enc + ((size_t)b * 2048 + key0 + kr) * 512 + D);
            }
        }
    };
    auto STORE = [&]() {
        if (BF16) {
            #pragma unroll
            for (int it = 0; it < 4; it++) {
                int off = it * 2048 + tid * 8;
                int kr = off >> 9, D = off & 511;
                us4 h0 = pf4[it * 2], h1 = pf4[it * 2 + 1];
                float4 lo = {bf2f(h0[0]), bf2f(h0[1]), bf2f(h0[2]), bf2f(h0[3])};
                float4 hi = {bf2f(h1[0]), bf2f(h1[1]), bf2f(h1[2]), bf2f(h1[3])};
                *(float4*)(rows + kr * 520 + D)     = lo;
                *(float4*)(rows + kr * 520 + D + 4) = hi;
            }
        } else {
            #pragma unroll
            for (int it = 0; it < 8; it++) {
                int off = it * 1024 + tid * 4;
                int kr = off >> 9, D = off & 511;
                *(float4*)(rows + kr * 520 + D) = pf32[it];
            }
        }
    };

    LOAD(0);
    __syncthreads();   // qts staged
    for (int g = 0; g < 8; g++) {
        STORE();
        if (g < 7) LOAD(g + 1);
        __syncthreads();
        {   // logits: 16 keys x 8 heads, 2-way K split
            int kr = tid >> 4, hh = (tid >> 1) & 7, part = tid & 1;
            const float* q = qts + hh * 520 + part * 256;
            const float* e = rows + kr * 520 + part * 256;
            float a0 = 0.f, a1 = 0.f, a2 = 0.f, a3 = 0.f;
            #pragma unroll
            for (int d = 0; d < 256; d += 16) {
                f32x4 q0 = *(const f32x4*)(q + d);      f32x4 e0 = *(const f32x4*)(e + d);
                f32x4 q1 = *(const f32x4*)(q + d + 4);  f32x4 e1 = *(const f32x4*)(e + d + 4);
                f32x4 q2 = *(const f32x4*)(q + d + 8);  f32x4 e2 = *(const f32x4*)(e + d + 8);
                f32x4 q3 = *(const f32x4*)(q + d + 12); f32x4 e3 = *(const f32x4*)(e + d + 12);
                a0 += q0[0]*e0[0] + q0[1]*e0[1] + q0[2]*e0[2] + q0[3]*e0[3];
                a1 += q1[0]*e1[0] + q1[1]*e1[1] + q1[2]*e1[2] + q1[3]*e1[3];
                a2 += q2[0]*e2[0] + q2[1]*e2[1] + q2[2]*e2[2] + q2[3]*e2[3];
                a3 += q3[0]*e3[0] + q3[1]*e3[1] + q3[2]*e3[2] + q3[3]*e3[3];
            }
            float acc = (a0 + a1) + (a2 + a3);
            acc += __shfl_xor(acc, 1);
            if (part == 0) {
                int key = c * 128 + g * 16 + kr;
                float pv = clf(A.pad + b * 2048 + key);
                lge[hh * 16 + kr] = (pv != 0.f) ? -2e30f : acc;
            }
        }
        __syncthreads();
        if (tid < 128) {   // online softmax update
            int hh = tid >> 4, k = tid & 15;
            float lv = lge[hh * 16 + k];
            float gm = lv;
            gm = fmaxf(gm, __shfl_xor(gm, 1));
            gm = fmaxf(gm, __shfl_xor(gm, 2));
            gm = fmaxf(gm, __shfl_xor(gm, 4));
            gm = fmaxf(gm, __shfl_xor(gm, 8));
            float mold = mhp[hh];
            float mnew = fmaxf(mold, gm);
            float ev = __expf(lv - mnew);
            float gs = ev;
            gs += __shfl_xor(gs, 1); gs += __shfl_xor(gs, 2);
            gs += __shfl_xor(gs, 4); gs += __shfl_xor(gs, 8);
            float f = __expf(mold - mnew);
            lge[hh * 16 + k] = ev;
            if (k == 0) { shp[hh] = shp[hh] * f + gs; mhp[hh] = mnew; fhp[hh] = f; }
        }
        __syncthreads();
        {   // z accumulation
            float f = fhp[h];
            #pragma unroll
            for (int jj = 0; jj < 4; jj++) z4[jj] *= f;
            #pragma unroll
            for (int k = 0; k < 16; k++) {
                float ev = lge[h * 16 + k];
                #pragma unroll
                for (int jj = 0; jj < 4; jj++) {
                    f32x4 rv = *(const f32x4*)(rows + k * 520 + jj * 128 + ii * 4);
                    z4[jj] += ev * rv;
                }
            }
        }
        __syncthreads();
    }
    int bc = b * 16 + c;
    if (tid < 8) { csf(A.Pm2 + bc * 8 + tid, mhp[tid]); csf(A.Ps2 + bc * 8 + tid, shp[tid]); }
    #pragma unroll
    for (int jj = 0; jj < 4; jj++) {
        float* dst = A.Pz + ((size_t)bc * 8 + h) * 512 + jj * 128 + ii * 4;
        csf2(dst,     z4[jj][0], z4[jj][1]);
        csf2(dst + 2, z4[jj][2], z4[jj][3]);
    }
}

// ---------------------------------------------------------------------------

__global__ __launch_bounds__(NTHR, 1) void k_mega(Args A) {
    __shared__ float sm[12700];
    const int bid = blockIdx.x, tid = threadIdx.x;
    const int lane = tid & 63, w = tid >> 6;

    // ---------------- P0: setup (posenc, padflag, enc->bf16) ---------------
    if (bid < 16) {
        int p = bid;
        #pragma unroll
        for (int k = 0; k < 2; k++) {
            int i = tid + k * 256;
            float expo = (2.0f * (float)(i >> 1)) * (1.f / 512.f);
            float f = powf(10000.0f, -expo);
            float ang = (float)p * f;
            csf(A.pos + p * 512 + i, ((i & 1) == 0) ? sinf(ang) : cosf(ang));
        }
    }
    if (bid < 128) {
        int kg = bid * 256 + tid;          // (b*2048+key)
        const float* p = A.encIn + (size_t)kg * 128;
        int ok = 1;
        for (int i = 0; i < 128; i += 4) {
            float4 v = *(const float4*)(p + i);
            ok &= (v.x == 0.f) & (v.y == 0.f) & (v.z == 0.f) & (v.w == 0.f);
        }
        csf(A.pad + kg, ok ? 1.f : 0.f);
    } else if (A.encbf) {
        int blk = bid - 128;
        for (int it = 0; it < 128; it++) {
            size_t vi = ((size_t)blk * 128 + it) * 256 + tid;
            float4 v = *(const float4*)(A.enc + vi * 4);
            us4 o; o[0] = f2bf(v.x); o[1] = f2bf(v.y); o[2] = f2bf(v.z); o[3] = f2bf(v.w);
            csu4(A.encbf + vi * 4, o);
        }
    }
    gsync(A.bar);

    for (int t = 0; t < 16; t++) {
        // ---------------- S_emb ----------------
        if (bid < 32) {
            int cb = bid >> 2, bq = bid & 3;
            int b = bq * 4 + w;
            float* tokw = sm + w * 256;
            #pragma unroll
            for (int i = 0; i < 4; i++)
                tokw[lane + i * 64] = (t == 0) ? 1.f
                    : clf(A.out + (size_t)b * 4096 + (t - 1) * 256 + lane + i * 64);
            __syncthreads();
            int col = cb * 64 + lane;
            float acc = wdot(tokw, A.embW, 256, col, 512) + A.embB[col];
            csf(A.x0 + (size_t)b * 512 + col,
                acc * 22.627416997969522f + clf(A.pos + t * 512 + col));
        }
        gsync(A.bar);

        for (int l = 0; l < 4; l++) {
            const float* src = (l == 0) ? A.x0 : A.y3;
            const float* gP = (l == 0) ? nullptr : A.lng + ((l - 1) * 3 + 2) * 512;
            const float* bP = (l == 0) ? nullptr : A.lnb + ((l - 1) * 3 + 2) * 512;
            int ulnP = (l != 0);

            // ---------------- S1: self q/k/v projections ----------------
            if (bid < 96) {
                int m = bid >> 5;               // 0=q 1=k 2=v
                int r = bid & 31;
                int cb = r >> 2, bq = r & 3;
                int b = bq * 4 + w;
                float* xsw = sm + w * 512;
                stage_ln_wave(src + (size_t)b * 512, gP, bP, ulnP, xsw, lane);
                __syncthreads();
                int col = cb * 64 + lane;
                const float* W = A.selfW + ((size_t)(l * 4 + m)) * 262144;
                float acc = wdot(xsw, W, 512, col, 512) + A.selfB[(l * 4 + m) * 512 + col];
                if (m == 0) csf(A.qbuf + (size_t)b * 512 + col, acc);
                else if (m == 1) csf(A.selfK + (((size_t)l * 16 + b) * 16 + t) * 512 + col, acc);
                else csf(A.selfV + (((size_t)l * 16 + b) * 16 + t) * 512 + col, acc);
            }
            gsync(A.bar);

            // ---------------- S2: self-attn + output proj (y1 = a + x) ----
            if (bid < 128) {
                int b = bid >> 3, cb = bid & 7;
                float* xr = sm; float* qs = sm + 512; float* as_ = sm + 1024;
                float* lg = sm + 1536; float* wsv = sm + 1664; float* part = sm + 1792;
                float* red = sm + 2056;
                ln512_block(src + (size_t)b * 512, gP, bP, ulnP, xr, red);
                for (int i = tid; i < 512; i += 256) qs[i] = clf(A.qbuf + (size_t)b * 512 + i);
                __syncthreads();
                const float* Kb = A.selfK + ((size_t)l * 16 + b) * 16 * 512;
                const float* Vb = A.selfV + ((size_t)l * 16 + b) * 16 * 512;
                if (tid < 128) {
                    int h = tid >> 4, j = tid & 15;
                    if (j <= t) {
                        const float* kr_ = Kb + (size_t)j * 512 + h * 64;
                        const float* qh_ = qs + h * 64;
                        float s0 = 0.f, s1 = 0.f;
                        #pragma unroll
                        for (int d = 0; d < 64; d += 4) {
                            float2 qa = *(const float2*)(qh_ + d);
                            float2 qb = *(const float2*)(qh_ + d + 2);
                            float2 ka = clf2(kr_ + d);
                            float2 kb = clf2(kr_ + d + 2);
                            s0 += qa.x * ka.x + qa.y * ka.y;
                            s1 += qb.x * kb.x + qb.y * kb.y;
                        }
                        lg[h * 16 + j] = (s0 + s1) * 0.125f;
                    }
                }
                __syncthreads();
                if (tid < 8) {
                    float m = -1e30f;
                    for (int j = 0; j <= t; j++) m = fmaxf(m, lg[tid * 16 + j]);
                    float ssum = 0.f;
                    for (int j = 0; j <= t; j++) {
                        float e = __expf(lg[tid * 16 + j] - m);
                        wsv[tid * 16 + j] = e; ssum += e;
                    }
                    float inv = 1.f / ssum;
                    for (int j = 0; j <= t; j++) wsv[tid * 16 + j] *= inv;
                }
                __syncthreads();
                for (int i = tid; i < 512; i += 256) {
                    int h = i >> 6;
                    float a = 0.f;
                    for (int j = 0; j <= t; j++)
                        a += wsv[h * 16 + j] * clf(Vb + (size_t)j * 512 + i);
                    as_[i] = a;
                }
                __syncthreads();
                const float* Wo = A.selfW + ((size_t)(l * 4 + 3)) * 262144;
                float racc = gemv_splitk(as_, Wo, cb * 64, 512, part);
                if (tid < 64) {
                    int col = cb * 64 + tid;
                    csf(A.y1 + (size_t)b * 512 + col,
                        racc + A.selfB[(l * 4 + 3) * 512 + col] + xr[col]);
                }
            }
            gsync(A.bar);

            // ---------------- S3: qc = LN(y1)@Wq_c + bq_c (store lny1) -----
            if (bid < 32) {
                int cb = bid >> 2, bq = bid & 3;
                int b = bq * 4 + w;
                float* xsw = sm + w * 512;
                stage_ln_wave(A.y1 + (size_t)b * 512, A.lng + (l * 3) * 512,
                              A.lnb + (l * 3) * 512, 1, xsw, lane);
                __syncthreads();
                if (cb == 0) {
                    #pragma unroll
                    for (int i = 0; i < 8; i++)
                        csf(A.lny1 + (size_t)b * 512 + lane + i * 64, xsw[lane + i * 64]);
                }
                int col = cb * 64 + lane;
                const float* Wq = A.crossW + ((size_t)(l * 4)) * 262144;
                float acc = wdot(xsw, Wq, 512, col, 512) + A.crossB[(l * 4) * 512 + col];
                csf(A.qc + (size_t)b * 512 + col, acc);
            }
            gsync(A.bar);

            // ---------------- S4: qt[b,h,:] = 0.125 * (qc_h @ Wk_h^T) ------
            if (bid < 128) {
                int b = bid >> 3, h = bid & 7;
                float* qh = sm;
                if (tid < 64) qh[tid] = clf(A.qc + (size_t)b * 512 + h * 64 + tid);
                __syncthreads();
                const float* Wk = A.crossW + ((size_t)(l * 4 + 1)) * 262144;
                #pragma unroll
                for (int pass = 0; pass < 2; pass++) {
                    int D = pass * 256 + tid;
                    const float* wr = Wk + (size_t)D * 512 + h * 64;
                    float a0 = 0.f, a1 = 0.f;
                    #pragma unroll
                    for (int dd = 0; dd < 64; dd += 8) {
                        f32x4 w0 = *(const f32x4*)(wr + dd);
                        f32x4 w1 = *(const f32x4*)(wr + dd + 4);
                        a0 += qh[dd]*w0[0] + qh[dd+1]*w0[1] + qh[dd+2]*w0[2] + qh[dd+3]*w0[3];
                        a1 += qh[dd+4]*w1[0] + qh[dd+5]*w1[1] + qh[dd+6]*w1[2] + qh[dd+7]*w1[3];
                    }
                    csf(A.qt + ((size_t)b * 8 + h) * 512 + D, (a0 + a1) * 0.125f);
                }
            }
            gsync(A.bar);

            // ---------------- S5: flash cross-attn over enc ----------------
            if (A.encbf) flash_stage<1>(A, sm, bid, tid);
            else         flash_stage<0>(A, sm, bid, tid);
            gsync(A.bar);

            // ---------------- S6: combine chunks + @Wv --------------------
            if (bid < 128) {
                int b = bid >> 3, h = bid & 7;
                float* zs = sm; float* part = sm + 1792;
                float mc[16], ec[16];
                float mm = -1e30f;
                #pragma unroll
                for (int cc = 0; cc < 16; cc++) {
                    mc[cc] = clf(A.Pm2 + (b * 16 + cc) * 8 + h); mm = fmaxf(mm, mc[cc]);
                }
                float S = 0.f;
                #pragma unroll
                for (int cc = 0; cc < 16; cc++) {
                    ec[cc] = __expf(mc[cc] - mm);
                    S += ec[cc] * clf(A.Ps2 + (b * 16 + cc) * 8 + h);
                }
                float inv = 1.f / S;
                for (int i = tid; i < 512; i += 256) {
                    float a = 0.f;
                    #pragma unroll
                    for (int cc = 0; cc < 16; cc++)
                        a += ec[cc] * clf(A.Pz + ((size_t)(b * 16 + cc) * 8 + h) * 512 + i);
                    zs[i] = a * inv;
                }
                __syncthreads();
                const float* Wv = A.crossW + ((size_t)(l * 4 + 2)) * 262144;
                float racc = gemv_splitk(zs, Wv, h * 64, 512, part);
                if (tid < 64)
                    csf(A.attnb + (size_t)b * 512 + h * 64 + tid,
                        racc + A.crossB[(l * 4 + 2) * 512 + h * 64 + tid]);
            }
            gsync(A.bar);

            // ---------------- S7: y2 = attnb@Wo_c + bo_c + lny1 ------------
            if (bid < 32) {
                int cb = bid >> 2, bq = bid & 3;
                int b = bq * 4 + w;
                float* xsw = sm + w * 512;
                #pragma unroll
                for (int i = 0; i < 8; i++)
                    xsw[lane + i * 64] = clf(A.attnb + (size_t)b * 512 + lane + i * 64);
                __syncthreads();
                int col = cb * 64 + lane;
                const float* Wco = A.crossW + ((size_t)(l * 4 + 3)) * 262144;
                float acc = wdot(xsw, Wco, 512, col, 512)
                          + A.crossB[(l * 4 + 3) * 512 + col]
                          + clf(A.lny1 + (size_t)b * 512 + col);
                csf(A.y2 + (size_t)b * 512 + col, acc);
            }
            gsync(A.bar);

            // ---------------- S8: ffn1 = relu(LN(y2)@W1+b1) (store lny2) ---
            if (bid < 128) {
                int cb = bid >> 2, bq = bid & 3;   // cb 0..31
                int b = bq * 4 + w;
                float* xsw = sm + w * 512;
                stage_ln_wave(A.y2 + (size_t)b * 512, A.lng + (l * 3 + 1) * 512,
                              A.lnb + (l * 3 + 1) * 512, 1, xsw, lane);
                __syncthreads();
                if (cb == 0) {
                    #pragma unroll
                    for (int i = 0; i < 8; i++)
                        csf(A.lny2 + (size_t)b * 512 + lane + i * 64, xsw[lane + i * 64]);
                }
                int col = cb * 64 + lane;
                const float* W1 = A.fW1 + (size_t)l * 512 * 2048;
                float acc = wdot(xsw, W1, 512, col, 2048) + A.fb1[l * 2048 + col];
                csf(A.tmpb + (size_t)b * 2048 + col, fmaxf(acc, 0.f));
            }
            gsync(A.bar);

            // ---------------- S9: y3 = tmpb@W2 + b2 + lny2 (split-K=2048) --
            if (bid < 128) {
                int b = bid >> 3, cb = bid & 7;
                float* ts = sm;            // 2048
                float* part = sm + 2048;   // 256
                for (int i = tid; i < 2048; i += 256)
                    ts[i] = clf(A.tmpb + (size_t)b * 2048 + i);
                __syncthreads();
                const float* W2 = A.fW2 + (size_t)l * 2048 * 512;
                int col = cb * 64 + lane;
                const float* Wp = W2 + ((size_t)(w * 512)) * 512 + col;
                const float* xp = ts + w * 512;
                float a0 = 0.f, a1 = 0.f, a2 = 0.f, a3 = 0.f;
                for (int r = 0; r < 512; r += 4) {
                    a0 += xp[r]     * Wp[(size_t)r * 512];
                    a1 += xp[r + 1] * Wp[(size_t)(r + 1) * 512];
                    a2 += xp[r + 2] * Wp[(size_t)(r + 2) * 512];
                    a3 += xp[r + 3] * Wp[(size_t)(r + 3) * 512];
                }
                part[w * 64 + lane] = (a0 + a1) + (a2 + a3);
                __syncthreads();
                if (tid < 64) {
                    float s = part[tid] + part[64 + tid] + part[128 + tid] + part[192 + tid];
                    int c2 = cb * 64 + tid;
                    csf(A.y3 + (size_t)b * 512 + c2,
                        s + A.fb2[l * 512 + c2] + clf(A.lny2 + (size_t)b * 512 + c2));
                }
            }
            gsync(A.bar);
        } // l

        // ---------------- S_out: logits for step t ----------------
        if (bid < 16) {
            int cb = bid >> 2, bq = bid & 3;
            int b = bq * 4 + w;
            float* xsw = sm + w * 512;
            stage_ln_wave(A.y3 + (size_t)b * 512, A.lng + 11 * 512, A.lnb + 11 * 512, 1, xsw, lane);
            __syncthreads();
            int col = cb * 64 + lane;
            float acc = wdot(xsw, A.outW, 512, col, 256) + A.outB[col];
            csf(A.out + (size_t)b * 4096 + t * 256 + col, acc);
        }
        gsync(A.bar);
    } // t
}

// ---------------------------------------------------------------------------

extern "C" void kernel_launch(void* const* d_in, const int* in_sizes, int n_in,
                              void* d_out, int out_size, void* d_ws, size_t ws_size,
                              hipStream_t stream) {
    Args A;
    A.enc    = (const float*)d_in[0];
    A.encIn  = (const float*)d_in[1];
    A.embW   = (const float*)d_in[2];
    A.embB   = (const float*)d_in[3];
    A.outW   = (const float*)d_in[4];
    A.outB   = (const float*)d_in[5];
    A.selfW  = (const float*)d_in[6];
    A.selfB  = (const float*)d_in[7];
    A.crossW = (const float*)d_in[8];
    A.crossB = (const float*)d_in[9];
    A.fW1    = (const float*)d_in[10];
    A.fb1    = (const float*)d_in[11];
    A.fW2    = (const float*)d_in[12];
    A.fb2    = (const float*)d_in[13];
    A.lng    = (const float*)d_in[14];
    A.lnb    = (const float*)d_in[15];
    A.out    = (float*)d_out;

    char* ws = (char*)d_ws;
    size_t off = 0;
    auto alloc = [&](size_t bytes) -> char* {
        char* p = ws + off;
        off = (off + bytes + 255) & ~(size_t)255;
        return p;
    };
    char* barrier = alloc(4096);
    A.bar = (unsigned*)barrier;
    A.pad   = (float*)alloc((size_t)16 * 2048 * 4);
    A.pos   = (float*)alloc(16 * 512 * 4);
    A.x0    = (float*)alloc(16 * 512 * 4);
    A.qbuf  = (float*)alloc(16 * 512 * 4);
    A.qc    = (float*)alloc(16 * 512 * 4);
    A.y1    = (float*)alloc(16 * 512 * 4);
    A.y2    = (float*)alloc(16 * 512 * 4);
    A.y3    = (float*)alloc(16 * 512 * 4);
    A.attnb = (float*)alloc(16 * 512 * 4);
    A.lny1  = (float*)alloc(16 * 512 * 4);
    A.lny2  = (float*)alloc(16 * 512 * 4);
    A.qt    = (float*)alloc((size_t)16 * 8 * 512 * 4);
    A.Pm2   = (float*)alloc(16 * 16 * 8 * 4);
    A.Ps2   = (float*)alloc(16 * 16 * 8 * 4);
    A.Pz    = (float*)alloc((size_t)16 * 16 * 8 * 512 * 4);
    A.tmpb  = (float*)alloc((size_t)16 * 2048 * 4);
    A.selfK = (float*)alloc((size_t)4 * 16 * 16 * 512 * 4);
    A.selfV = (float*)alloc((size_t)4 * 16 * 16 * 512 * 4);
    size_t small_need = off;
    A.encbf = nullptr;
    if (off + (size_t)16 * 2048 * 512 * 2 + 512 <= ws_size)
        A.encbf = (ushort_t*)alloc((size_t)16 * 2048 * 512 * 2);
    if (small_need > ws_size) return;   // ws absurdly small -> zero output

    hipMemsetAsync(barrier, 0, 4096, stream);   // barrier state must start at 0
    k_mega<<<dim3(NB), dim3(NTHR), 0, stream>>>(A);
}

// Round 6
// 9738.785 us; speedup vs baseline: 8.3934x; 2.1252x over previous
//
#include <hip/hip_runtime.h>

// ---------------------------------------------------------------------------
// Decoder_49005576847865 — persistent single-kernel incremental decoder.
//   B=16, d=512, H=8 (dh=64), L=4, dff=2048, Lenc=2048, 16 steps, vocab=256.
// Round 6: fix memory-latency exposure (round 5: 1 wave/SIMD + 8B atomic
//   enc loads => 150 GB/s effective on 3 GB of traffic).
//   * 1024-thread blocks (16 waves/CU), 256 blocks (1 block/CU).
//   * write-once buffers (encbf/pad/pos/selfK/V/out) -> plain cached
//     vector loads; only mutable activations use agent-scope atomics.
//   * all weight GEMVs: float4 loads, deep split-K, LDS partial reduce.
//   * merged qc+qt stage; 545 grid barriers (fence-free, relaxed tree).
// ---------------------------------------------------------------------------

typedef unsigned short ushort_t;
typedef __attribute__((ext_vector_type(4))) float f32x4;
typedef __attribute__((ext_vector_type(8))) unsigned short us8;
typedef __attribute__((ext_vector_type(4))) unsigned short us4;

#define NB 256
#define NTHR 1024

__device__ __forceinline__ float bf2f(ushort_t u) {
    union { unsigned int i; float f; } v; v.i = ((unsigned int)u) << 16; return v.f;
}
__device__ __forceinline__ ushort_t f2bf(float f) {
    union { unsigned int i; float f; } v; v.f = f;
    return (ushort_t)((v.i + 0x7FFF + ((v.i >> 16) & 1)) >> 16);   // RNE
}
__device__ __forceinline__ float wave_sum(float v) {
    #pragma unroll
    for (int m = 32; m; m >>= 1) v += __shfl_xor(v, m);
    return v;
}

// ---- coherent (agent-scope, fence-free) access for MUTABLE activations -----
union U64C { unsigned long long u; float2 f; us4 s4; };
__device__ __forceinline__ float clf(const float* p) {
    return __hip_atomic_load(p, __ATOMIC_RELAXED, __HIP_MEMORY_SCOPE_AGENT);
}
__device__ __forceinline__ void csf(float* p, float v) {
    __hip_atomic_store(p, v, __ATOMIC_RELAXED, __HIP_MEMORY_SCOPE_AGENT);
}
__device__ __forceinline__ float2 clf2(const float* p) {
    U64C c; c.u = __hip_atomic_load((unsigned long long*)p, __ATOMIC_RELAXED,
                                    __HIP_MEMORY_SCOPE_AGENT);
    return c.f;
}
__device__ __forceinline__ void csf2(float* p, float x, float y) {
    U64C c; c.f.x = x; c.f.y = y;
    __hip_atomic_store((unsigned long long*)p, c.u, __ATOMIC_RELAXED,
                       __HIP_MEMORY_SCOPE_AGENT);
}
__device__ __forceinline__ void csu4(ushort_t* p, us4 v) {
    U64C c; c.s4 = v;
    __hip_atomic_store((unsigned long long*)p, c.u, __ATOMIC_RELAXED,
                       __HIP_MEMORY_SCOPE_AGENT);
}

// ---- fence-free grid barrier (round-5 protocol, verified correct) ----------
__device__ __forceinline__ void gsync(unsigned* bar) {
    __syncthreads();
    if (threadIdx.x == 0) {
        unsigned grp = blockIdx.x & 7u;
        unsigned* sub = bar + 32 + grp * 32;
        unsigned* rel = bar + 32 * 9;
        unsigned s = __hip_atomic_fetch_add(sub, 1u, __ATOMIC_RELAXED,
                                            __HIP_MEMORY_SCOPE_AGENT);
        unsigned e = s >> 5;                 // 32 blocks per sub-group
        bool fin = false;
        if ((s & 31u) == 31u) {
            unsigned a = __hip_atomic_fetch_add(bar, 1u, __ATOMIC_RELAXED,
                                                __HIP_MEMORY_SCOPE_AGENT);
            if ((a & 7u) == 7u) {
                #pragma unroll
                for (int i = 0; i < 8; i++)
                    __hip_atomic_store(rel + i * 32, e + 1u, __ATOMIC_RELAXED,
                                       __HIP_MEMORY_SCOPE_AGENT);
                fin = true;
            }
        }
        if (!fin) {
            unsigned* myrel = rel + grp * 32;
            while ((int)(__hip_atomic_load(myrel, __ATOMIC_RELAXED,
                                           __HIP_MEMORY_SCOPE_AGENT) - (e + 1u)) < 0)
                __builtin_amdgcn_s_sleep(2);
        }
    }
    __syncthreads();
}

// ---- block-wide LN of one 512 row (1024 threads; first 512 carry data) -----
__device__ __forceinline__ void ln512b(const float* __restrict__ row,
                                       const float* __restrict__ g,
                                       const float* __restrict__ be,
                                       int use_ln, float* dst, float* red) {
    int tid = threadIdx.x;
    float a = (tid < 512) ? clf(row + tid) : 0.f;
    if (use_ln) {
        float s = wave_sum(a);
        if ((tid & 63) == 0) red[tid >> 6] = s;
        __syncthreads();
        float tot = 0.f;
        #pragma unroll
        for (int i = 0; i < 16; i++) tot += red[i];
        float mu = tot * (1.f / 512.f);
        float d = (tid < 512) ? (a - mu) : 0.f;
        float v = wave_sum(d * d);
        __syncthreads();
        if ((tid & 63) == 0) red[tid >> 6] = v;
        __syncthreads();
        float vt = 0.f;
        #pragma unroll
        for (int i = 0; i < 16; i++) vt += red[i];
        float rstd = rsqrtf(vt * (1.f / 512.f) + 1e-6f);
        if (tid < 512) dst[tid] = d * rstd * g[tid] + be[tid];
    } else {
        if (tid < 512) dst[tid] = a;
    }
    __syncthreads();
}

// ---- block GEMV core: NC=NCQ*4 cols, S k-slices of KS rows (NCQ*S=1024) ----
template<int NCQ, int S, int KS>
__device__ __forceinline__ void gemv_block(const float* xs, const float* __restrict__ W,
                                           int ldw, int col0, float* part) {
    int tid = threadIdx.x;
    int ct = tid & (NCQ - 1);
    int ks = tid / NCQ;
    int colq = col0 + ct * 4;
    const float* Wp = W + (size_t)(ks * KS) * ldw + colq;
    const float* xp = xs + ks * KS;
    f32x4 acc = {0.f, 0.f, 0.f, 0.f};
    #pragma unroll 8
    for (int r = 0; r < KS; r++) {
        f32x4 wv = *(const f32x4*)(Wp + (size_t)r * ldw);
        acc += xp[r] * wv;
    }
    *(f32x4*)(part + ks * (NCQ * 4) + ct * 4) = acc;
    __syncthreads();
}
template<int NC, int S>
__device__ __forceinline__ float gemv_reduce(const float* part) {
    int tid = threadIdx.x;   // caller ensures tid < NC
    float acc = 0.f;
    #pragma unroll
    for (int s = 0; s < S; s++) acc += part[s * NC + tid];
    return acc;
}

struct Args {
    const float *enc, *encIn, *embW, *embB, *outW, *outB;
    const float *selfW, *selfB, *crossW, *crossB;
    const float *fW1, *fb1, *fW2, *fb2, *lng, *lnb;
    float* out;
    unsigned* bar;
    float *pad, *pos, *x0, *qbuf, *y1, *y2, *y3, *attnb;
    float *lny1, *lny2, *qt, *Pm2, *Ps2, *Pz, *tmpb, *selfK, *selfV;
    ushort_t* encbf;
};

// ---- flash cross-attn stage (block = (b, 128-key chunk), 1024 threads) -----
template<int BF16>
__device__ __forceinline__ void flash_stage(const Args& A, float* sm, int bid, int tid) {
    int b = bid >> 4, c = bid & 15;
    float* qts  = sm;             // [8][520]
    float* rows = sm + 4160;      // [32][520]
    float* lge  = sm + 20800;     // [8][32]
    float* mhp  = sm + 21056;
    float* shp  = sm + 21064;
    float* fhp  = sm + 21072;
    #pragma unroll
    for (int it = 0; it < 2; it++) {          // qt staging via 8B coherent loads
        int p = tid + it * 1024;               // pair index 0..2047
        float2 v = clf2(A.qt + (size_t)b * 4096 + p * 2);
        int el = p * 2;
        int r = el >> 9, d = el & 511;
        qts[r * 520 + d] = v.x;
        qts[r * 520 + d + 1] = v.y;
    }
    if (tid < 8) { mhp[tid] = -1e30f; shp[tid] = 0.f; fhp[tid] = 1.f; }
    int hz = tid >> 7, ii = tid & 127;
    f32x4 z = {0.f, 0.f, 0.f, 0.f};
    __syncthreads();

    for (int g = 0; g < 4; g++) {             // 4 groups of 32 keys
        int key0 = c * 128 + g * 32;
        if (BF16) {
            #pragma unroll
            for (int it = 0; it < 2; it++) {
                int idx = tid + it * 1024;     // 2048 chunks of 8 bf16
                int kr = idx >> 6, D = (idx & 63) * 8;
                us8 v = *(const us8*)(A.encbf + ((size_t)b * 2048 + key0 + kr) * 512 + D);
                float* rp = rows + kr * 520 + D;
                rp[0] = bf2f(v[0]); rp[1] = bf2f(v[1]); rp[2] = bf2f(v[2]); rp[3] = bf2f(v[3]);
                rp[4] = bf2f(v[4]); rp[5] = bf2f(v[5]); rp[6] = bf2f(v[6]); rp[7] = bf2f(v[7]);
            }
        } else {
            #pragma unroll
            for (int it = 0; it < 4; it++) {
                int idx = tid + it * 1024;     // 4096 chunks of 4 f32
                int kr = idx >> 7, D = (idx & 127) * 4;
                float4 v = *(const float4*)(A.enc + ((size_t)b * 2048 + key0 + kr) * 512 + D);
                *(float4*)(rows + kr * 520 + D) = v;
            }
        }
        __syncthreads();
        {   // logits: 32 keys x 8 heads x 4 K-parts
            int kr = tid >> 5, hh = (tid >> 2) & 7, part = tid & 3;
            const float* q = qts + hh * 520 + part * 128;
            const float* e = rows + kr * 520 + part * 128;
            float a0 = 0.f, a1 = 0.f, a2 = 0.f, a3 = 0.f;
            #pragma unroll
            for (int d = 0; d < 128; d += 16) {
                f32x4 q0 = *(const f32x4*)(q + d);      f32x4 e0 = *(const f32x4*)(e + d);
                f32x4 q1 = *(const f32x4*)(q + d + 4);  f32x4 e1 = *(const f32x4*)(e + d + 4);
                f32x4 q2 = *(const f32x4*)(q + d + 8);  f32x4 e2 = *(const f32x4*)(e + d + 8);
                f32x4 q3 = *(const f32x4*)(q + d + 12); f32x4 e3 = *(const f32x4*)(e + d + 12);
                a0 += q0[0]*e0[0] + q0[1]*e0[1] + q0[2]*e0[2] + q0[3]*e0[3];
                a1 += q1[0]*e1[0] + q1[1]*e1[1] + q1[2]*e1[2] + q1[3]*e1[3];
                a2 += q2[0]*e2[0] + q2[1]*e2[1] + q2[2]*e2[2] + q2[3]*e2[3];
                a3 += q3[0]*e3[0] + q3[1]*e3[1] + q3[2]*e3[2] + q3[3]*e3[3];
            }
            float acc = (a0 + a1) + (a2 + a3);
            acc += __shfl_xor(acc, 1);
            acc += __shfl_xor(acc, 2);
            if (part == 0) {
                float pv = A.pad[b * 2048 + key0 + kr];   // cached read
                lge[hh * 32 + kr] = (pv != 0.f) ? -2e30f : acc;
            }
        }
        __syncthreads();
        if (tid < 256) {   // online softmax: 8 h x 32 k
            int hh = tid >> 5, k = tid & 31;
            float lv = lge[hh * 32 + k];
            float gm = lv;
            gm = fmaxf(gm, __shfl_xor(gm, 1));
            gm = fmaxf(gm, __shfl_xor(gm, 2));
            gm = fmaxf(gm, __shfl_xor(gm, 4));
            gm = fmaxf(gm, __shfl_xor(gm, 8));
            gm = fmaxf(gm, __shfl_xor(gm, 16));
            float mold = mhp[hh];
            float mnew = fmaxf(mold, gm);
            float ev = __expf(lv - mnew);
            float gs = ev;
            gs += __shfl_xor(gs, 1); gs += __shfl_xor(gs, 2);
            gs += __shfl_xor(gs, 4); gs += __shfl_xor(gs, 8);
            gs += __shfl_xor(gs, 16);
            float f = __expf(mold - mnew);
            lge[hh * 32 + k] = ev;
            if (k == 0) { shp[hh] = shp[hh] * f + gs; mhp[hh] = mnew; fhp[hh] = f; }
        }
        __syncthreads();
        {   // z accumulation: thread = (head hz, 4-float slot ii)
            float f = fhp[hz];
            z *= f;
            const float* rp = rows + ii * 4;
            #pragma unroll
            for (int k = 0; k < 32; k++) {
                float ev = lge[hz * 32 + k];
                f32x4 rv = *(const f32x4*)(rp + k * 520);
                z += ev * rv;
            }
        }
        __syncthreads();
    }
    int bc = b * 16 + c;
    if (tid < 8) { csf(A.Pm2 + bc * 8 + tid, mhp[tid]); csf(A.Ps2 + bc * 8 + tid, shp[tid]); }
    float* dst = A.Pz + ((size_t)bc * 8 + hz) * 512 + ii * 4;
    csf2(dst, z[0], z[1]);
    csf2(dst + 2, z[2], z[3]);
}

// ---------------------------------------------------------------------------

__global__ __launch_bounds__(NTHR, 1) void k_mega(Args A) {
    __shared__ float sm[21120];   // 84.5 KB -> 1 block/CU
    const int bid = blockIdx.x, tid = threadIdx.x;
    float* red = sm + 1792;
    float* part = sm + 2048;

    // ---------------- P0: setup ----------------
    if (bid < 8) {   // positional encodings: 16*512
        int idx = bid * 1024 + tid;
        int p = idx >> 9, i = idx & 511;
        float expo = (2.0f * (float)(i >> 1)) * (1.f / 512.f);
        float f = powf(10000.0f, -expo);
        float ang = (float)p * f;
        csf(A.pos + p * 512 + i, ((i & 1) == 0) ? sinf(ang) : cosf(ang));
    }
    {   // pad flags: 128 per block (8 threads each)
        int fl = bid * 128 + (tid >> 3);
        int sub = tid & 7;
        const float* p = A.encIn + (size_t)fl * 128 + sub * 16;
        int ok = 1;
        #pragma unroll
        for (int j = 0; j < 4; j++) {
            float4 v = *(const float4*)(p + j * 4);
            ok &= (v.x == 0.f) & (v.y == 0.f) & (v.z == 0.f) & (v.w == 0.f);
        }
        ok &= __shfl_xor(ok, 1); ok &= __shfl_xor(ok, 2); ok &= __shfl_xor(ok, 4);
        if (sub == 0) csf(A.pad + fl, ok ? 1.f : 0.f);
    }
    if (A.encbf) {   // enc -> bf16: 64 elems per thread
        size_t base = ((size_t)bid * 1024 + tid) * 64;
        #pragma unroll 4
        for (int it = 0; it < 16; it++) {
            float4 v = *(const float4*)(A.enc + base + it * 4);
            us4 o; o[0] = f2bf(v.x); o[1] = f2bf(v.y); o[2] = f2bf(v.z); o[3] = f2bf(v.w);
            csu4(A.encbf + base + it * 4, o);
        }
    }
    gsync(A.bar);

    for (int t = 0; t < 16; t++) {
        // ---------------- S_emb: x0 = tok@embW*sqrt(d)+pos ----------------
        if (bid < 16) {
            int b = bid;
            float* tok = sm;
            if (tid < 256)
                tok[tid] = (t == 0) ? 1.f
                         : clf(A.out + (size_t)b * 4096 + (t - 1) * 256 + tid);
            __syncthreads();
            gemv_block<128, 8, 32>(tok, A.embW, 512, 0, part);
            if (tid < 512) {
                float acc = gemv_reduce<512, 8>(part) + A.embB[tid];
                csf(A.x0 + (size_t)b * 512 + tid,
                    acc * 22.627416997969522f + A.pos[t * 512 + tid]);
            }
        }
        gsync(A.bar);

        for (int l = 0; l < 4; l++) {
            const float* src = (l == 0) ? A.x0 : A.y3;
            const float* gP = (l == 0) ? nullptr : A.lng + ((l - 1) * 3 + 2) * 512;
            const float* bP = (l == 0) ? nullptr : A.lnb + ((l - 1) * 3 + 2) * 512;
            int ulnP = (l != 0);

            // ---------------- S1: self q/k/v projections -------------------
            if (bid < 96) {
                int m = bid >> 5, r = bid & 31;
                int b = r >> 1, ch = r & 1;
                float* xs = sm;
                ln512b(src + (size_t)b * 512, gP, bP, ulnP, xs, red);
                gemv_block<64, 16, 32>(xs, A.selfW + ((size_t)(l * 4 + m)) * 262144,
                                       512, ch * 256, part);
                if (tid < 256) {
                    int col = ch * 256 + tid;
                    float acc = gemv_reduce<256, 16>(part) + A.selfB[(l * 4 + m) * 512 + col];
                    if (m == 0) csf(A.qbuf + (size_t)b * 512 + col, acc);
                    else if (m == 1)
                        csf(A.selfK + (((size_t)l * 16 + b) * 16 + t) * 512 + col, acc);
                    else
                        csf(A.selfV + (((size_t)l * 16 + b) * 16 + t) * 512 + col, acc);
                }
            }
            gsync(A.bar);

            // ---------------- S2: self-attn + Wo proj + residual -----------
            if (bid < 32) {
                int b = bid >> 1, ch = bid & 1;
                float* xr = sm; float* qs = sm + 512; float* as_ = sm + 1024;
                float* lg = sm + 1536; float* wsv = sm + 1664;
                ln512b(src + (size_t)b * 512, gP, bP, ulnP, xr, red);
                if (tid < 512) qs[tid] = clf(A.qbuf + (size_t)b * 512 + tid);
                __syncthreads();
                const float* Kb = A.selfK + ((size_t)l * 16 + b) * 16 * 512;
                const float* Vb = A.selfV + ((size_t)l * 16 + b) * 16 * 512;
                if (tid < 128) {
                    int h = tid >> 4, j = tid & 15;
                    if (j <= t) {
                        const float* kr_ = Kb + (size_t)j * 512 + h * 64;
                        const float* qh_ = qs + h * 64;
                        float s0 = 0.f, s1 = 0.f;
                        #pragma unroll
                        for (int d = 0; d < 64; d += 8) {
                            f32x4 qa = *(const f32x4*)(qh_ + d);
                            f32x4 ka = *(const f32x4*)(kr_ + d);
                            f32x4 qb = *(const f32x4*)(qh_ + d + 4);
                            f32x4 kb = *(const f32x4*)(kr_ + d + 4);
                            s0 += qa[0]*ka[0] + qa[1]*ka[1] + qa[2]*ka[2] + qa[3]*ka[3];
                            s1 += qb[0]*kb[0] + qb[1]*kb[1] + qb[2]*kb[2] + qb[3]*kb[3];
                        }
                        lg[h * 16 + j] = (s0 + s1) * 0.125f;
                    }
                }
                __syncthreads();
                if (tid < 8) {
                    float m = -1e30f;
                    for (int j = 0; j <= t; j++) m = fmaxf(m, lg[tid * 16 + j]);
                    float ssum = 0.f;
                    for (int j = 0; j <= t; j++) {
                        float e = __expf(lg[tid * 16 + j] - m);
                        wsv[tid * 16 + j] = e; ssum += e;
                    }
                    float inv = 1.f / ssum;
                    for (int j = 0; j <= t; j++) wsv[tid * 16 + j] *= inv;
                }
                __syncthreads();
                if (tid < 512) {
                    int h = tid >> 6;
                    float a = 0.f;
                    for (int j = 0; j <= t; j++)
                        a += wsv[h * 16 + j] * Vb[(size_t)j * 512 + tid];
                    as_[tid] = a;
                }
                __syncthreads();
                gemv_block<64, 16, 32>(as_, A.selfW + ((size_t)(l * 4 + 3)) * 262144,
                                       512, ch * 256, part);
                if (tid < 256) {
                    int col = ch * 256 + tid;
                    float acc = gemv_reduce<256, 16>(part);
                    csf(A.y1 + (size_t)b * 512 + col,
                        acc + A.selfB[(l * 4 + 3) * 512 + col] + xr[col]);
                }
            }
            gsync(A.bar);

            // ---------------- S34: qc_h then qt (merged) -------------------
            if (bid < 128) {
                int b = bid >> 3, h = bid & 7;
                float* xsw = sm;
                float* qch = sm + 1824;   // 64
                ln512b(A.y1 + (size_t)b * 512, A.lng + (l * 3) * 512,
                       A.lnb + (l * 3) * 512, 1, xsw, red);
                if (h == 0 && tid < 512)
                    csf(A.lny1 + (size_t)b * 512 + tid, xsw[tid]);
                gemv_block<16, 64, 8>(xsw, A.crossW + ((size_t)(l * 4)) * 262144,
                                      512, h * 64, part);
                if (tid < 64)
                    qch[tid] = gemv_reduce<64, 64>(part) + A.crossB[(l * 4) * 512 + h * 64 + tid];
                __syncthreads();
                {   // qt[b,h,D] = 0.125 * qch . Wk[D][h*64..]
                    int D = tid >> 1, half = tid & 1;
                    const float* wr = A.crossW + ((size_t)(l * 4 + 1)) * 262144
                                    + (size_t)D * 512 + h * 64 + half * 32;
                    const float* qp = qch + half * 32;
                    float a0 = 0.f, a1 = 0.f;
                    #pragma unroll
                    for (int j = 0; j < 8; j += 2) {
                        f32x4 w0 = *(const f32x4*)(wr + j * 4);
                        f32x4 w1 = *(const f32x4*)(wr + j * 4 + 4);
                        a0 += qp[j*4]*w0[0] + qp[j*4+1]*w0[1] + qp[j*4+2]*w0[2] + qp[j*4+3]*w0[3];
                        a1 += qp[j*4+4]*w1[0] + qp[j*4+5]*w1[1] + qp[j*4+6]*w1[2] + qp[j*4+7]*w1[3];
                    }
                    float v = a0 + a1;
                    v += __shfl_xor(v, 1);
                    if (half == 0)
                        csf(A.qt + ((size_t)b * 8 + h) * 512 + D, v * 0.125f);
                }
            }
            gsync(A.bar);

            // ---------------- S5: flash cross-attn over enc ----------------
            if (A.encbf) flash_stage<1>(A, sm, bid, tid);
            else         flash_stage<0>(A, sm, bid, tid);
            gsync(A.bar);

            // ---------------- S6: combine chunks + @Wv ---------------------
            if (bid < 128) {
                int b = bid >> 3, h = bid & 7;
                float* zs = sm;           // 512
                float* zs2 = sm + 512;    // 2 x 512
                float* ecs = sm + 1600;   // 17
                if (tid < 16) {
                    float mcv = clf(A.Pm2 + (b * 16 + tid) * 8 + h);
                    float mm = mcv;
                    mm = fmaxf(mm, __shfl_xor(mm, 1));
                    mm = fmaxf(mm, __shfl_xor(mm, 2));
                    mm = fmaxf(mm, __shfl_xor(mm, 4));
                    mm = fmaxf(mm, __shfl_xor(mm, 8));
                    float ec = __expf(mcv - mm);
                    float sv = ec * clf(A.Ps2 + (b * 16 + tid) * 8 + h);
                    sv += __shfl_xor(sv, 1); sv += __shfl_xor(sv, 2);
                    sv += __shfl_xor(sv, 4); sv += __shfl_xor(sv, 8);
                    ecs[tid] = ec;
                    if (tid == 0) ecs[16] = 1.f / sv;
                }
                __syncthreads();
                {
                    int D = tid & 511, chf = tid >> 9;
                    float a = 0.f;
                    #pragma unroll
                    for (int j = 0; j < 8; j++) {
                        int cc = chf * 8 + j;
                        a += ecs[cc] * clf(A.Pz + ((size_t)(b * 16 + cc) * 8 + h) * 512 + D);
                    }
                    zs2[chf * 512 + D] = a;
                }
                __syncthreads();
                if (tid < 512) zs[tid] = (zs2[tid] + zs2[512 + tid]) * ecs[16];
                __syncthreads();
                gemv_block<16, 64, 8>(zs, A.crossW + ((size_t)(l * 4 + 2)) * 262144,
                                      512, h * 64, part);
                if (tid < 64)
                    csf(A.attnb + (size_t)b * 512 + h * 64 + tid,
                        gemv_reduce<64, 64>(part) + A.crossB[(l * 4 + 2) * 512 + h * 64 + tid]);
            }
            gsync(A.bar);

            // ---------------- S7: y2 = attnb@Wco + bco + lny1 --------------
            if (bid < 32) {
                int b = bid >> 1, ch = bid & 1;
                float* xsw = sm;
                if (tid < 512) xsw[tid] = clf(A.attnb + (size_t)b * 512 + tid);
                __syncthreads();
                gemv_block<64, 16, 32>(xsw, A.crossW + ((size_t)(l * 4 + 3)) * 262144,
                                       512, ch * 256, part);
                if (tid < 256) {
                    int col = ch * 256 + tid;
                    float acc = gemv_reduce<256, 16>(part)
                              + A.crossB[(l * 4 + 3) * 512 + col]
                              + clf(A.lny1 + (size_t)b * 512 + col);
                    csf(A.y2 + (size_t)b * 512 + col, acc);
                }
            }
            gsync(A.bar);

            // ---------------- S8: tmpb = relu(LN(y2)@W1+b1) ----------------
            if (bid < 128) {
                int b = bid >> 3, cq = bid & 7;
                float* xsw = sm;
                ln512b(A.y2 + (size_t)b * 512, A.lng + (l * 3 + 1) * 512,
                       A.lnb + (l * 3 + 1) * 512, 1, xsw, red);
                if (cq == 0 && tid < 512)
                    csf(A.lny2 + (size_t)b * 512 + tid, xsw[tid]);
                gemv_block<64, 16, 32>(xsw, A.fW1 + (size_t)l * 512 * 2048,
                                       2048, cq * 256, part);
                if (tid < 256) {
                    int col = cq * 256 + tid;
                    float acc = gemv_reduce<256, 16>(part) + A.fb1[l * 2048 + col];
                    csf(A.tmpb + (size_t)b * 2048 + col, fmaxf(acc, 0.f));
                }
            }
            gsync(A.bar);

            // ---------------- S9: y3 = tmpb@W2 + b2 + lny2 -----------------
            if (bid < 64) {
                int b = bid >> 2, cq = bid & 3;
                float* ts = sm;   // 2048
                #pragma unroll
                for (int it = 0; it < 2; it++) {
                    int p = tid + it * 1024;
                    ts[p] = clf(A.tmpb + (size_t)b * 2048 + p);
                }
                __syncthreads();
                gemv_block<32, 32, 64>(ts, A.fW2 + (size_t)l * 2048 * 512,
                                       512, cq * 128, part);
                if (tid < 128) {
                    int col = cq * 128 + tid;
                    float acc = gemv_reduce<128, 32>(part) + A.fb2[l * 512 + col]
                              + clf(A.lny2 + (size_t)b * 512 + col);
                    csf(A.y3 + (size_t)b * 512 + col, acc);
                }
            }
            gsync(A.bar);
        } // l

        // ---------------- S_out: logits for step t ----------------
        if (bid < 16) {
            int b = bid;
            float* xsw = sm;
            ln512b(A.y3 + (size_t)b * 512, A.lng + 11 * 512, A.lnb + 11 * 512, 1, xsw, red);
            gemv_block<64, 16, 32>(xsw, A.outW, 256, 0, part);
            if (tid < 256) {
                float acc = gemv_reduce<256, 16>(part) + A.outB[tid];
                csf(A.out + (size_t)b * 4096 + t * 256 + tid, acc);
            }
        }
        gsync(A.bar);
    } // t
}

// ---------------------------------------------------------------------------

extern "C" void kernel_launch(void* const* d_in, const int* in_sizes, int n_in,
                              void* d_out, int out_size, void* d_ws, size_t ws_size,
                              hipStream_t stream) {
    Args A;
    A.enc    = (const float*)d_in[0];
    A.encIn  = (const float*)d_in[1];
    A.embW   = (const float*)d_in[2];
    A.embB   = (const float*)d_in[3];
    A.outW   = (const float*)d_in[4];
    A.outB   = (const float*)d_in[5];
    A.selfW  = (const float*)d_in[6];
    A.selfB  = (const float*)d_in[7];
    A.crossW = (const float*)d_in[8];
    A.crossB = (const float*)d_in[9];
    A.fW1    = (const float*)d_in[10];
    A.fb1    = (const float*)d_in[11];
    A.fW2    = (const float*)d_in[12];
    A.fb2    = (const float*)d_in[13];
    A.lng    = (const float*)d_in[14];
    A.lnb    = (const float*)d_in[15];
    A.out    = (float*)d_out;

    char* ws = (char*)d_ws;
    size_t off = 0;
    auto alloc = [&](size_t bytes) -> char* {
        char* p = ws + off;
        off = (off + bytes + 255) & ~(size_t)255;
        return p;
    };
    char* barrier = alloc(4096);
    A.bar = (unsigned*)barrier;
    A.pad   = (float*)alloc((size_t)16 * 2048 * 4);
    A.pos   = (float*)alloc(16 * 512 * 4);
    A.x0    = (float*)alloc(16 * 512 * 4);
    A.qbuf  = (float*)alloc(16 * 512 * 4);
    A.y1    = (float*)alloc(16 * 512 * 4);
    A.y2    = (float*)alloc(16 * 512 * 4);
    A.y3    = (float*)alloc(16 * 512 * 4);
    A.attnb = (float*)alloc(16 * 512 * 4);
    A.lny1  = (float*)alloc(16 * 512 * 4);
    A.lny2  = (float*)alloc(16 * 512 * 4);
    A.qt    = (float*)alloc((size_t)16 * 8 * 512 * 4);
    A.Pm2   = (float*)alloc(16 * 16 * 8 * 4);
    A.Ps2   = (float*)alloc(16 * 16 * 8 * 4);
    A.Pz    = (float*)alloc((size_t)16 * 16 * 8 * 512 * 4);
    A.tmpb  = (float*)alloc((size_t)16 * 2048 * 4);
    A.selfK = (float*)alloc((size_t)4 * 16 * 16 * 512 * 4);
    A.selfV = (float*)alloc((size_t)4 * 16 * 16 * 512 * 4);
    size_t small_need = off;
    A.encbf = nullptr;
    if (off + (size_t)16 * 2048 * 512 * 2 + 512 <= ws_size)
        A.encbf = (ushort_t*)alloc((size_t)16 * 2048 * 512 * 2);
    if (small_need > ws_size) return;   // ws absurdly small -> zero output

    hipMemsetAsync(barrier, 0, 4096, stream);   // barrier state must start at 0
    k_mega<<<dim3(NB), dim3(NTHR), 0, stream>>>(A);
}